// Round 16
// baseline (346.211 us; speedup 1.0000x reference)
//
#include <hip/hip_runtime.h>

typedef __attribute__((ext_vector_type(4))) float f32x4;
typedef __attribute__((ext_vector_type(8))) short short8;
typedef unsigned short ushort_t;

__device__ __forceinline__ float bf2f(ushort_t u) {
  unsigned int i = ((unsigned int)u) << 16;
  return __builtin_bit_cast(float, i);
}
__device__ __forceinline__ ushort_t f2bf(float f) {
  unsigned int x = __builtin_bit_cast(unsigned int, f);
  unsigned int r = (x + 0x7FFFu + ((x >> 16) & 1u)) >> 16;
  return (ushort_t)r;
}

// ---------------- fused fp32 -> bf16 convert: all 9 inputs in one launch ----------------
__global__ __launch_bounds__(256)
void cvt_all(const float* __restrict__ x, const float* __restrict__ wcq,
             const float* __restrict__ wdqn, const float* __restrict__ wdqr,
             const float* __restrict__ wckv, const float* __restrict__ wdkn,
             const float* __restrict__ wdv, const float* __restrict__ wkr,
             const float* __restrict__ wpr,
             ushort_t* ox, ushort_t* owcq, ushort_t* owdqn, ushort_t* owdqr,
             ushort_t* owckv, ushort_t* owdkn, ushort_t* owdv, ushort_t* owkr,
             ushort_t* owpr) {
  int bid = blockIdx.x;
  const float* in; ushort_t* out;
  if (bid < 8192)       { in = x;    out = ox;    }
  else if (bid < 11264) { in = wcq;  out = owcq;  bid -= 8192;  }
  else if (bid < 12800) { in = wdqn; out = owdqn; bid -= 11264; }
  else if (bid < 14336) { in = wdqr; out = owdqr; bid -= 12800; }
  else if (bid < 15360) { in = wckv; out = owckv; bid -= 14336; }
  else if (bid < 15872) { in = wdkn; out = owdkn; bid -= 15360; }
  else if (bid < 16896) { in = wdv;  out = owdv;  bid -= 15872; }
  else if (bid < 17024) { in = wkr;  out = owkr;  bid -= 16896; }
  else                  { in = wpr;  out = owpr;  bid -= 17024; }
  const long i = ((long)bid * 256 + threadIdx.x) * 4;
  float4 v = *(const float4*)(in + i);
  ushort4 o;
  o.x = f2bf(v.x); o.y = f2bf(v.y); o.z = f2bf(v.z); o.w = f2bf(v.w);
  *(ushort4*)(out + i) = o;
}

// ---------------- bf16 MFMA GEMM (single-output, fp32 or bf16 out) ----------------
template <int OUT_BF16>
__global__ __launch_bounds__(256)
void gemm_bt(const ushort_t* __restrict__ A, const ushort_t* __restrict__ B,
             void* __restrict__ Cv, int M, int N, int K) {
  __shared__ __align__(16) ushort_t As[128 * 64];
  __shared__ __align__(16) ushort_t Bs[128 * 64];
  const int tid = threadIdx.x;
  const int lane = tid & 63;
  const int wid = tid >> 6;
  const int m0 = blockIdx.y * 128;
  const int n0 = blockIdx.x * 128;
  const int wm = (wid >> 1) * 64;
  const int wn = (wid & 1) * 64;

  f32x4 acc[4][4];
#pragma unroll
  for (int m = 0; m < 4; ++m)
#pragma unroll
    for (int n = 0; n < 4; ++n) acc[m][n] = (f32x4){0.f, 0.f, 0.f, 0.f};

  const int ktiles = K >> 6;
  for (int kt = 0; kt < ktiles; ++kt) {
    const int k0 = kt << 6;
    __syncthreads();
#pragma unroll
    for (int i = 0; i < 4; ++i) {
      const int chunk = (i * 4 + wid) * 1024;
      const int o = chunk + lane * 16;
      const int row = o >> 7;
      const int cb = o & 127;
      const ushort_t* src = A + (long)(m0 + row) * K + (k0 + (cb >> 1));
      __builtin_amdgcn_global_load_lds((const __attribute__((address_space(1))) unsigned int*)src,
                                       (__attribute__((address_space(3))) unsigned int*)((char*)As + chunk),
                                       16, 0, 0);
    }
#pragma unroll
    for (int i = 0; i < 4; ++i) {
      const int chunk = (i * 4 + wid) * 1024;
      const int o = chunk + lane * 16;
      const int row = o >> 7;
      const int cb = o & 127;
      int brow = n0 + row;
      if (brow > N - 1) brow = N - 1;
      const ushort_t* src = B + (long)brow * K + (k0 + (cb >> 1));
      __builtin_amdgcn_global_load_lds((const __attribute__((address_space(1))) unsigned int*)src,
                                       (__attribute__((address_space(3))) unsigned int*)((char*)Bs + chunk),
                                       16, 0, 0);
    }
    __syncthreads();
#pragma unroll
    for (int kk = 0; kk < 2; ++kk) {
      const int kb = kk * 32 + ((lane >> 4) << 3);
      short8 a[4], b[4];
#pragma unroll
      for (int m = 0; m < 4; ++m)
        a[m] = *(const short8*)(As + (wm + m * 16 + (lane & 15)) * 64 + kb);
#pragma unroll
      for (int n = 0; n < 4; ++n)
        b[n] = *(const short8*)(Bs + (wn + n * 16 + (lane & 15)) * 64 + kb);
#pragma unroll
      for (int m = 0; m < 4; ++m)
#pragma unroll
        for (int n = 0; n < 4; ++n)
          acc[m][n] = __builtin_amdgcn_mfma_f32_16x16x32_bf16(a[m], b[n], acc[m][n], 0, 0, 0);
    }
  }
  const int rb = m0 + wm + ((lane >> 4) << 2);
  const int cbase = n0 + wn + (lane & 15);
#pragma unroll
  for (int m = 0; m < 4; ++m)
#pragma unroll
    for (int n = 0; n < 4; ++n) {
      const int c = cbase + n * 16;
      if (c < N) {
#pragma unroll
        for (int j = 0; j < 4; ++j) {
          const long r = rb + m * 16 + j;
          if (OUT_BF16)
            ((ushort_t*)Cv)[r * N + c] = f2bf(acc[m][n][j]);
          else
            ((float*)Cv)[r * N + c] = acc[m][n][j];
        }
      }
    }
}

// ---------------- merged 3-output GEMM (x-projections) ----------------
__global__ __launch_bounds__(256)
void gemm_bt3(const ushort_t* __restrict__ A,
              const ushort_t* __restrict__ B0, ushort_t* __restrict__ C0, int nb0, int N0,
              const ushort_t* __restrict__ B1, ushort_t* __restrict__ C1, int nb1, int N1,
              const ushort_t* __restrict__ B2, ushort_t* __restrict__ C2, int N2,
              int K) {
  __shared__ __align__(16) ushort_t As[128 * 64];
  __shared__ __align__(16) ushort_t Bs[128 * 64];
  int bx = blockIdx.x;
  const ushort_t* Bp; ushort_t* Cp; int N;
  if (bx < nb0)            { Bp = B0; Cp = C0; N = N0; }
  else if (bx < nb0 + nb1) { Bp = B1; Cp = C1; N = N1; bx -= nb0; }
  else                     { Bp = B2; Cp = C2; N = N2; bx -= nb0 + nb1; }
  const int tid = threadIdx.x;
  const int lane = tid & 63;
  const int wid = tid >> 6;
  const int m0 = blockIdx.y * 128;
  const int n0 = bx * 128;
  const int wm = (wid >> 1) * 64;
  const int wn = (wid & 1) * 64;

  f32x4 acc[4][4];
#pragma unroll
  for (int m = 0; m < 4; ++m)
#pragma unroll
    for (int n = 0; n < 4; ++n) acc[m][n] = (f32x4){0.f, 0.f, 0.f, 0.f};

  const int ktiles = K >> 6;
  for (int kt = 0; kt < ktiles; ++kt) {
    const int k0 = kt << 6;
    __syncthreads();
#pragma unroll
    for (int i = 0; i < 4; ++i) {
      const int chunk = (i * 4 + wid) * 1024;
      const int o = chunk + lane * 16;
      const int row = o >> 7;
      const int cb = o & 127;
      const ushort_t* src = A + (long)(m0 + row) * K + (k0 + (cb >> 1));
      __builtin_amdgcn_global_load_lds((const __attribute__((address_space(1))) unsigned int*)src,
                                       (__attribute__((address_space(3))) unsigned int*)((char*)As + chunk),
                                       16, 0, 0);
    }
#pragma unroll
    for (int i = 0; i < 4; ++i) {
      const int chunk = (i * 4 + wid) * 1024;
      const int o = chunk + lane * 16;
      const int row = o >> 7;
      const int cb = o & 127;
      int brow = n0 + row;
      if (brow > N - 1) brow = N - 1;
      const ushort_t* src = Bp + (long)brow * K + (k0 + (cb >> 1));
      __builtin_amdgcn_global_load_lds((const __attribute__((address_space(1))) unsigned int*)src,
                                       (__attribute__((address_space(3))) unsigned int*)((char*)Bs + chunk),
                                       16, 0, 0);
    }
    __syncthreads();
#pragma unroll
    for (int kk = 0; kk < 2; ++kk) {
      const int kb = kk * 32 + ((lane >> 4) << 3);
      short8 a[4], b[4];
#pragma unroll
      for (int m = 0; m < 4; ++m)
        a[m] = *(const short8*)(As + (wm + m * 16 + (lane & 15)) * 64 + kb);
#pragma unroll
      for (int n = 0; n < 4; ++n)
        b[n] = *(const short8*)(Bs + (wn + n * 16 + (lane & 15)) * 64 + kb);
#pragma unroll
      for (int m = 0; m < 4; ++m)
#pragma unroll
        for (int n = 0; n < 4; ++n)
          acc[m][n] = __builtin_amdgcn_mfma_f32_16x16x32_bf16(a[m], b[n], acc[m][n], 0, 0, 0);
    }
  }
  const int rb = m0 + wm + ((lane >> 4) << 2);
  const int cbase = n0 + wn + (lane & 15);
#pragma unroll
  for (int m = 0; m < 4; ++m)
#pragma unroll
    for (int n = 0; n < 4; ++n) {
      const int c = cbase + n * 16;
      if (c < N) {
#pragma unroll
        for (int j = 0; j < 4; ++j) {
          const long r = rb + m * 16 + j;
          Cp[r * N + c] = f2bf(acc[m][n][j]);
        }
      }
    }
}

// ---------------- merged 4-output GEMM (q & kv projections; per-segment A,K) ----------------
__global__ __launch_bounds__(256)
void gemm_qkv(const ushort_t* __restrict__ nq, const ushort_t* __restrict__ nkv,
              const ushort_t* __restrict__ wdqn, ushort_t* __restrict__ qnope,
              const ushort_t* __restrict__ wdqr, ushort_t* __restrict__ qr,
              const ushort_t* __restrict__ wdkn, ushort_t* __restrict__ knope,
              const ushort_t* __restrict__ wdv, ushort_t* __restrict__ vt) {
  __shared__ __align__(16) ushort_t S[16384];  // As | Bs ; reused 32KB for transpose epilogue
  ushort_t* As = S;
  ushort_t* Bs = S + 8192;
  int bx = blockIdx.x;
  const ushort_t* Ap; const ushort_t* Bp; ushort_t* Cp; int N, K; bool tv = false;
  if (bx < 8)       { Ap = nq;  K = 1536; Bp = wdqn; Cp = qnope; N = 1024; }
  else if (bx < 16) { Ap = nq;  K = 1536; Bp = wdqr; Cp = qr;    N = 1024; bx -= 8; }
  else if (bx < 24) { Ap = nkv; K = 512;  Bp = wdkn; Cp = knope; N = 1024; bx -= 16; }
  else              { Ap = nkv; K = 512;  Bp = wdv;  Cp = vt;    N = 2048; bx -= 24; tv = true; }
  const int tid = threadIdx.x;
  const int lane = tid & 63;
  const int wid = tid >> 6;
  const int m0 = blockIdx.y * 128;
  const int n0 = bx * 128;
  const int wm = (wid >> 1) * 64;
  const int wn = (wid & 1) * 64;

  f32x4 acc[4][4];
#pragma unroll
  for (int m = 0; m < 4; ++m)
#pragma unroll
    for (int n = 0; n < 4; ++n) acc[m][n] = (f32x4){0.f, 0.f, 0.f, 0.f};

  const int ktiles = K >> 6;
  for (int kt = 0; kt < ktiles; ++kt) {
    const int k0 = kt << 6;
    __syncthreads();
#pragma unroll
    for (int i = 0; i < 4; ++i) {
      const int chunk = (i * 4 + wid) * 1024;
      const int o = chunk + lane * 16;
      const int row = o >> 7;
      const int cb = o & 127;
      const ushort_t* src = Ap + (long)(m0 + row) * K + (k0 + (cb >> 1));
      __builtin_amdgcn_global_load_lds((const __attribute__((address_space(1))) unsigned int*)src,
                                       (__attribute__((address_space(3))) unsigned int*)((char*)As + chunk),
                                       16, 0, 0);
    }
#pragma unroll
    for (int i = 0; i < 4; ++i) {
      const int chunk = (i * 4 + wid) * 1024;
      const int o = chunk + lane * 16;
      const int row = o >> 7;
      const int cb = o & 127;
      const ushort_t* src = Bp + (long)(n0 + row) * K + (k0 + (cb >> 1));
      __builtin_amdgcn_global_load_lds((const __attribute__((address_space(1))) unsigned int*)src,
                                       (__attribute__((address_space(3))) unsigned int*)((char*)Bs + chunk),
                                       16, 0, 0);
    }
    __syncthreads();
#pragma unroll
    for (int kk = 0; kk < 2; ++kk) {
      const int kb = kk * 32 + ((lane >> 4) << 3);
      short8 a[4], b[4];
#pragma unroll
      for (int m = 0; m < 4; ++m)
        a[m] = *(const short8*)(As + (wm + m * 16 + (lane & 15)) * 64 + kb);
#pragma unroll
      for (int n = 0; n < 4; ++n)
        b[n] = *(const short8*)(Bs + (wn + n * 16 + (lane & 15)) * 64 + kb);
#pragma unroll
      for (int m = 0; m < 4; ++m)
#pragma unroll
        for (int n = 0; n < 4; ++n)
          acc[m][n] = __builtin_amdgcn_mfma_f32_16x16x32_bf16(a[m], b[n], acc[m][n], 0, 0, 0);
    }
  }
  if (tv) {
    __syncthreads();
    const int lrb = wm + ((lane >> 4) << 2);
    const int ldb = wn + (lane & 15);
#pragma unroll
    for (int m = 0; m < 4; ++m)
#pragma unroll
      for (int n = 0; n < 4; ++n) {
        const int ld = ldb + n * 16;
#pragma unroll
        for (int j = 0; j < 4; ++j) {
          const int lr = lrb + m * 16 + j;
          *(ushort_t*)((char*)S + lr * 256 + ((2 * ld) ^ ((lr & 15) << 4))) = f2bf(acc[m][n][j]);
        }
      }
    __syncthreads();
    const int b = m0 >> 11;
    const int s0 = m0 & 2047;
    const int bh = b * 16 + bx;
    const int d = tid & 127;
    const int sh = (tid >> 7) * 64;
#pragma unroll
    for (int i = 0; i < 8; ++i) {
      const int sbase = sh + i * 8;
      short8 val;
#pragma unroll
      for (int j = 0; j < 8; ++j) {
        const int s = sbase + j;
        val[j] = (short)*(const ushort_t*)((const char*)S + s * 256 + ((2 * d) ^ ((s & 15) << 4)));
      }
      *(short8*)(Cp + ((long)bh * 128 + d) * 2048 + s0 + sbase) = val;
    }
    return;
  }
  const int rb = m0 + wm + ((lane >> 4) << 2);
  const int cbase = n0 + wn + (lane & 15);
#pragma unroll
  for (int m = 0; m < 4; ++m)
#pragma unroll
    for (int n = 0; n < 4; ++n) {
      const int c = cbase + n * 16;
#pragma unroll
      for (int j = 0; j < 4; ++j) {
        const long r = rb + m * 16 + j;
        Cp[r * N + c] = f2bf(acc[m][n][j]);
      }
    }
}

// ---------------- rmsnorm + rope_kraw merged ----------------
__device__ __forceinline__ void rms_body(const ushort_t* x, const float* w,
                                         ushort_t* out, int R, float* warr) {
  const int tid = threadIdx.x;
  float ss = 0.f;
  for (int i = tid; i < R; i += 256) { float v = bf2f(x[i]); ss += v * v; }
#pragma unroll
  for (int off = 32; off; off >>= 1) ss += __shfl_xor(ss, off);
  if ((tid & 63) == 0) warr[tid >> 6] = ss;
  __syncthreads();
  const float tot = warr[0] + warr[1] + warr[2] + warr[3];
  const float rs = rsqrtf(tot / (float)R + 1e-6f);
  for (int i = tid; i < R; i += 256) out[i] = f2bf(bf2f(x[i]) * rs * w[i]);
}

__device__ __forceinline__ void rope_body(const ushort_t* in, ushort_t* out,
                                          const float* fc, const float* fs,
                                          int heads, int bid) {
  const int idx = bid * 256 + threadIdx.x;
  const int i = idx & 31;
  const int rest = idx >> 5;
  const int hh = rest % heads;
  const int row = rest / heads;
  const int srow = row & 2047;
  const float c = fc[srow * 32 + i];
  const float s = fs[srow * 32 + i];
  const long base = (long)row * heads * 64 + hh * 64 + 2 * i;
  const float x0 = bf2f(in[base]);
  const float x1 = bf2f(in[base + 1]);
  out[base] = f2bf(x0 * c - x1 * s);
  out[base + 1] = f2bf(x0 * s + x1 * c);
}

__global__ __launch_bounds__(256)
void rms_rope(const ushort_t* __restrict__ ckv, const float* __restrict__ kvnw,
              ushort_t* __restrict__ nkv,
              const ushort_t* __restrict__ cq, const float* __restrict__ qnw,
              ushort_t* __restrict__ nq,
              const ushort_t* __restrict__ kraw, ushort_t* __restrict__ qrs,
              const float* __restrict__ fc, const float* __restrict__ fs) {
  __shared__ float warr[4];
  const int bid = blockIdx.x;
  if (bid < 4096) rms_body(ckv + (long)bid * 512, kvnw, nkv + (long)bid * 512, 512, warr);
  else if (bid < 8192) {
    const long row = bid - 4096;
    rms_body(cq + row * 1536, qnw, nq + row * 1536, 1536, warr);
  } else {
    rope_body(kraw, qrs, fc, fs, 1, bid - 8192);
  }
}

__global__ __launch_bounds__(256)
void rope_qr(const ushort_t* __restrict__ qr, ushort_t* __restrict__ krope,
             const float* __restrict__ fc, const float* __restrict__ fs) {
  rope_body(qr, krope, fc, fs, 16, blockIdx.x);
}

// ---------------- MFMA flash attention v9: KVBLK=128 + wave-role stagger ----------------
// As v8, but waves 0-3 run {QK(t+1); process(t)} while waves 4-7 run
// {process(t); QK(t+1)} -> each SIMD (hosting one wave of each half) keeps the
// MFMA and VALU/LDS pipes simultaneously busy. Orders are hazard-equivalent.
__global__ __launch_bounds__(512)
void attn_mfma(const ushort_t* __restrict__ qn, const ushort_t* __restrict__ qrs,
               const ushort_t* __restrict__ kn, const ushort_t* __restrict__ kr,
               const ushort_t* __restrict__ vt, ushort_t* __restrict__ out) {
  __shared__ __align__(16) ushort_t Ks[2][16384];   // [128 k][128 d], rows 256B, swizzled
  __shared__ __align__(16) ushort_t Vts[2][16384];  // [128 d][128 s], rows 256B, swizzled
  __shared__ __align__(16) ushort_t Ps[8192];       // per-wave [16 q][64 k] = 2048B x 8 waves
  const int tid = threadIdx.x, lane = tid & 63, wid = tid >> 6;
  const int g = lane >> 4, lq = lane & 15;
  const int bh = blockIdx.x, b = bh >> 4, h = bh & 15;
  const float scale = 0.08838834764831845f;  // 1/sqrt(128)
  char* Pbase = (char*)Ps + wid * 2048;

  auto stageK = [&](int bsel, int kt) {
    const int k0s = kt * 128;
#pragma unroll
    for (int i = 0; i < 4; ++i) {
      const int cc = wid * 4 + i;
      const int o = cc * 1024 + lane * 16;
      const int row = o >> 8;
      const int dK = ((o & 255) ^ ((row & 7) << 4)) >> 1;
      const long krow = (long)b * 2048 + k0s + row;
      const ushort_t* srcK = (dK < 64) ? (kn + krow * 1024 + h * 64 + dK)
                                       : (kr + krow * 1024 + h * 64 + (dK - 64));
      __builtin_amdgcn_global_load_lds((const __attribute__((address_space(1))) unsigned int*)srcK,
          (__attribute__((address_space(3))) unsigned int*)((char*)Ks[bsel] + cc * 1024), 16, 0, 0);
    }
  };
  auto stageV = [&](int bsel, int kt) {
    const int k0s = kt * 128;
#pragma unroll
    for (int i = 0; i < 4; ++i) {
      const int cc = wid * 4 + i;
      const int o = cc * 1024 + lane * 16;
      const int dr = o >> 8;
      const int se = ((o & 255) ^ ((dr & 7) << 4)) >> 1;
      const ushort_t* srcV = vt + ((long)bh * 128 + dr) * 2048 + k0s + se;
      __builtin_amdgcn_global_load_lds((const __attribute__((address_space(1))) unsigned int*)srcV,
          (__attribute__((address_space(3))) unsigned int*)((char*)Vts[bsel] + cc * 1024), 16, 0, 0);
    }
  };

  const int pair = blockIdx.y;
  for (int half = 0; half < 2; ++half) {
    const int tq = half ? (15 - pair) : pair;  // 128-row q-tile index
    const int q0 = tq * 128;
    const int qw0 = q0 + wid * 16;
    short8 aq[4];
    {
      const long grow = (long)b * 2048 + qw0 + lq;
#pragma unroll
      for (int ks = 0; ks < 4; ++ks) {
        const int d = ks * 32 + g * 8;
        const ushort_t* src = (d < 64) ? (qn + grow * 1024 + h * 64 + d)
                                       : (qrs + grow * 64 + (d - 64));
        aq[ks] = *(const short8*)src;
      }
    }
    f32x4 oacc[8];
#pragma unroll
    for (int n = 0; n < 8; ++n) oacc[n] = (f32x4){0.f, 0.f, 0.f, 0.f};
    float sm[4] = {-3e38f, -3e38f, -3e38f, -3e38f};
    float sl[4] = {0.f, 0.f, 0.f, 0.f};

    auto qk = [&](f32x4 (&sacc)[8], int u) {
#pragma unroll
      for (int n = 0; n < 8; ++n) sacc[n] = (f32x4){0.f, 0.f, 0.f, 0.f};
      const ushort_t* Kbuf = Ks[u & 1];
      __builtin_amdgcn_s_setprio(1);
#pragma unroll
      for (int ks = 0; ks < 4; ++ks) {
        const int x = ks * 64 + g * 16;
#pragma unroll
        for (int n = 0; n < 8; ++n) {
          const int kl = n * 16 + lq;
          short8 bk = *(const short8*)((const char*)Kbuf + kl * 256 + (x ^ ((kl & 7) << 4)));
          sacc[n] = __builtin_amdgcn_mfma_f32_16x16x32_bf16(aq[ks], bk, sacc[n], 0, 0, 0);
        }
      }
      __builtin_amdgcn_s_setprio(0);
    };
    auto process = [&](f32x4 (&sacc)[8], int u) {
      const int k0 = u * 128;
      if (k0 + 127 > qw0) {  // causal mask (wave-uniform condition)
#pragma unroll
        for (int n = 0; n < 8; ++n) {
          const int key = k0 + n * 16 + lq;
#pragma unroll
          for (int j = 0; j < 4; ++j) {
            const int qrow = qw0 + g * 4 + j;
            if (key > qrow) sacc[n][j] = -3e38f;
          }
        }
      }
      float tmax[4];
#pragma unroll
      for (int j = 0; j < 4; ++j) {
        float t0 = fmaxf(fmaxf(sacc[0][j], sacc[1][j]), fmaxf(sacc[2][j], sacc[3][j]));
        float t1 = fmaxf(fmaxf(sacc[4][j], sacc[5][j]), fmaxf(sacc[6][j], sacc[7][j]));
        tmax[j] = fmaxf(t0, t1);
      }
#pragma unroll
      for (int off = 1; off < 16; off <<= 1)
#pragma unroll
        for (int j = 0; j < 4; ++j) tmax[j] = fmaxf(tmax[j], __shfl_xor(tmax[j], off));
      bool need = false;
#pragma unroll
      for (int j = 0; j < 4; ++j) {
        tmax[j] *= scale;
        need = need || (tmax[j] > sm[j] + 8.f);
      }
      if (__any(need)) {
#pragma unroll
        for (int j = 0; j < 4; ++j) {
          const float mn = fmaxf(sm[j], tmax[j]);
          const float fr = __expf(sm[j] - mn);
          sm[j] = mn;
          sl[j] *= fr;
#pragma unroll
          for (int n = 0; n < 8; ++n) oacc[n][j] *= fr;
        }
      }
      f32x4 p[8];
#pragma unroll
      for (int n = 0; n < 8; ++n)
#pragma unroll
        for (int j = 0; j < 4; ++j)
          p[n][j] = __expf(__builtin_fmaf(sacc[n][j], scale, -sm[j]));
      float psum[4];
#pragma unroll
      for (int j = 0; j < 4; ++j) {
        psum[j] = ((p[0][j] + p[1][j]) + (p[2][j] + p[3][j])) +
                  ((p[4][j] + p[5][j]) + (p[6][j] + p[7][j]));
      }
#pragma unroll
      for (int off = 1; off < 16; off <<= 1)
#pragma unroll
        for (int j = 0; j < 4; ++j) psum[j] += __shfl_xor(psum[j], off);
#pragma unroll
      for (int j = 0; j < 4; ++j) sl[j] += psum[j];
      const ushort_t* Vbuf = Vts[u & 1];
#pragma unroll
      for (int hh = 0; hh < 2; ++hh) {
#pragma unroll
        for (int nn = 0; nn < 4; ++nn) {
          const int n = hh * 4 + nn;
          const int col2 = (nn * 16 + lq) * 2;
#pragma unroll
          for (int j = 0; j < 4; ++j) {
            const int row = g * 4 + j;
            *(ushort_t*)(Pbase + row * 128 + (col2 ^ ((row & 7) << 4))) = f2bf(p[n][j]);
          }
        }
        __builtin_amdgcn_s_setprio(1);
#pragma unroll
        for (int ks2 = 0; ks2 < 2; ++ks2) {
          const int x = ks2 * 64 + g * 16;
          short8 pa = *(const short8*)(Pbase + lq * 128 + (x ^ ((lq & 7) << 4)));
          const int xv = (hh * 2 + ks2) * 64 + g * 16;
#pragma unroll
          for (int nd = 0; nd < 8; ++nd) {
            const int dl = nd * 16 + lq;
            short8 vb = *(const short8*)((const char*)Vbuf + dl * 256 + (xv ^ ((dl & 7) << 4)));
            oacc[nd] = __builtin_amdgcn_mfma_f32_16x16x32_bf16(pa, vb, oacc[nd], 0, 0, 0);
          }
        }
        __builtin_amdgcn_s_setprio(0);
      }
    };

    const int kmax = tq + 1;  // 128-key tiles (may be odd)
    f32x4 saccA[8], saccB[8];
    // prologue
    stageK(0, 0); stageV(0, 0);
    if (kmax > 1) stageK(1, 1);
    asm volatile("s_waitcnt vmcnt(0)" ::: "memory");
    __builtin_amdgcn_s_barrier();
    __builtin_amdgcn_sched_barrier(0);
    qk(saccA, 0);
    const bool qkFirst = (wid < 4);  // one wave of each role per SIMD
    int u = 0;
    for (; u + 1 < kmax; u += 2) {
      // ---- phase even: tile u ----
      if (u + 2 < kmax) stageK(0, u + 2);
      stageV(1, u + 1);
      if (qkFirst) {
        qk(saccB, u + 1);      // MFMA reads Ks[1]
        process(saccA, u);     // VALU + PV reads Vts[0]
      } else {
        process(saccA, u);
        qk(saccB, u + 1);
      }
      asm volatile("s_waitcnt vmcnt(0)" ::: "memory");
      __builtin_amdgcn_s_barrier();
      __builtin_amdgcn_sched_barrier(0);
      // ---- phase odd: tile u+1 ----
      if (u + 3 < kmax) stageK(1, u + 3);
      if (u + 2 < kmax) stageV(0, u + 2);
      if (qkFirst) {
        if (u + 2 < kmax) qk(saccA, u + 2);
        process(saccB, u + 1);
      } else {
        process(saccB, u + 1);
        if (u + 2 < kmax) qk(saccA, u + 2);
      }
      asm volatile("s_waitcnt vmcnt(0)" ::: "memory");
      __builtin_amdgcn_s_barrier();
      __builtin_amdgcn_sched_barrier(0);
    }
    if (u < kmax) {  // odd kmax: final tile (even parity -> saccA, Vts[0])
      process(saccA, u);
      __builtin_amdgcn_s_barrier();  // all reads done before next half restages
    }
    // ---- epilogue for this q-tile ----
    float inv[4];
#pragma unroll
    for (int j = 0; j < 4; ++j) inv[j] = 1.f / sl[j];
#pragma unroll
    for (int nd = 0; nd < 8; ++nd) {
      const int d = nd * 16 + lq;
#pragma unroll
      for (int j = 0; j < 4; ++j) {
        const long row = (long)b * 2048 + qw0 + g * 4 + j;
        out[row * 2048 + h * 128 + d] = f2bf(oacc[nd][j] * inv[j]);
      }
    }
  }
}

// ---------------- launch ----------------
// Workspace: EXACTLY 101,711,872 B (round-3-proven bound).
extern "C" void kernel_launch(void* const* d_in, const int* in_sizes, int n_in,
                              void* d_out, int out_size, void* d_ws, size_t ws_size,
                              hipStream_t stream) {
  const float* x      = (const float*)d_in[0];
  const float* fcos   = (const float*)d_in[1];
  const float* fsin   = (const float*)d_in[2];
  const float* w_cq   = (const float*)d_in[3];
  const float* w_dqn  = (const float*)d_in[4];
  const float* w_dqr  = (const float*)d_in[5];
  const float* w_ckv  = (const float*)d_in[6];
  const float* w_dkn  = (const float*)d_in[7];
  const float* w_dv   = (const float*)d_in[8];
  const float* w_kr   = (const float*)d_in[9];
  const float* w_proj = (const float*)d_in[10];
  const float* qnw    = (const float*)d_in[11];
  const float* kvnw   = (const float*)d_in[12];
  float* out = (float*)d_out;

  char* ws = (char*)d_ws;
  ushort_t* x_bf     = (ushort_t*)(ws + 0);
  ushort_t* wcq_bf   = (ushort_t*)(ws + 16777216);  // dead after step 2
  ushort_t* qrs_bf   = (ushort_t*)(ws + 16777216);  //   written step 3, read step 6
  ushort_t* wdqn_bf  = (ushort_t*)(ws + 23068672);
  ushort_t* wdqr_bf  = (ushort_t*)(ws + 26214400);
  ushort_t* wckv_bf  = (ushort_t*)(ws + 29360128);
  ushort_t* wdkn_bf  = (ushort_t*)(ws + 31457280);
  ushort_t* wdv_bf   = (ushort_t*)(ws + 32505856);
  ushort_t* wpr_bf   = (ushort_t*)(ws + 34603008);
  ushort_t* cq_bf    = (ushort_t*)(ws + 42991616);  // CQ region
  ushort_t* krope_bf = (ushort_t*)(ws + 42991616);  //   after cq dead (rope_qr, step 5)
  ushort_t* ckv_bf   = (ushort_t*)(ws + 55574528);  // CKVNQ region
  ushort_t* nq_bf    = (ushort_t*)(ws + 59768832);
  ushort_t* attn_bf  = (ushort_t*)(ws + 55574528);  //   after ckv/nq dead (step 6)
  ushort_t* nkv_bf   = (ushort_t*)(ws + 72351744);
  ushort_t* qnope_bf = (ushort_t*)(ws + 76546048);  // QNOPE region
  ushort_t* kraw_bf  = (ushort_t*)(ws + 76546048);  //   before qnope written (step 4)
  ushort_t* qr_bf    = (ushort_t*)(ws + 0);         // X region, after x_bf dead
  ushort_t* knope_bf = (ushort_t*)(ws + 8388608);
  ushort_t* wkr_bf   = (ushort_t*)(ws + 84934656);  // V region (dead after step 2)
  ushort_t* vt_bf    = (ushort_t*)(ws + 84934656);  //   vt written step 4

  // 1. all converts
  cvt_all<<<21120, 256, 0, stream>>>(x, w_cq, w_dqn, w_dqr, w_ckv, w_dkn, w_dv, w_kr, w_proj,
                                     x_bf, wcq_bf, wdqn_bf, wdqr_bf, wckv_bf, wdkn_bf,
                                     wdv_bf, wkr_bf, wpr_bf);
  // 2. merged x-projections: [ckv 4 | cq 12 | kraw 1] blocks, K=2048
  gemm_bt3<<<dim3(17, 32), 256, 0, stream>>>(x_bf,
                                             wckv_bf, ckv_bf, 4, 512,
                                             wcq_bf, cq_bf, 12, 1536,
                                             wkr_bf, kraw_bf, 64, 2048);
  // 3. rmsnorms + rope kraw->qrs
  rms_rope<<<8704, 256, 0, stream>>>(ckv_bf, kvnw, nkv_bf, cq_bf, qnw, nq_bf,
                                     kraw_bf, qrs_bf, fcos, fsin);
  // 4. merged q+kv projections: [qnope 8 | qr 8 | knope 8 | vt 16]
  gemm_qkv<<<dim3(40, 32), 256, 0, stream>>>(nq_bf, nkv_bf,
                                             wdqn_bf, qnope_bf,
                                             wdqr_bf, qr_bf,
                                             wdkn_bf, knope_bf,
                                             wdv_bf, vt_bf);
  // 5. rope qr -> krope
  rope_qr<<<8192, 256, 0, stream>>>(qr_bf, krope_bf, fcos, fsin);
  // 6. MFMA flash attention v9 (KVBLK=128 + wave-role stagger)
  attn_mfma<<<dim3(32, 8), 512, 0, stream>>>(qnope_bf, qrs_bf, knope_bf, krope_bf, vt_bf, attn_bf);
  // 7. final projection (fp32 out)
  gemm_bt<0><<<dim3(16, 32), 256, 0, stream>>>(attn_bf, wpr_bf, out, 4096, 2048, 2048);
}

// Round 17
// 338.140 us; speedup vs baseline: 1.0239x; 1.0239x over previous
//
#include <hip/hip_runtime.h>

typedef __attribute__((ext_vector_type(4))) float f32x4;
typedef __attribute__((ext_vector_type(8))) short short8;
typedef unsigned short ushort_t;

__device__ __forceinline__ float bf2f(ushort_t u) {
  unsigned int i = ((unsigned int)u) << 16;
  return __builtin_bit_cast(float, i);
}
__device__ __forceinline__ ushort_t f2bf(float f) {
  unsigned int x = __builtin_bit_cast(unsigned int, f);
  unsigned int r = (x + 0x7FFFu + ((x >> 16) & 1u)) >> 16;
  return (ushort_t)r;
}

// ---------------- fused fp32 -> bf16 convert: all 9 inputs, 8 elems/thread ----------------
// Blocks (2048 elems each): x 4096 | wcq 1536 | wdqn 768 | wdqr 768 | wckv 512 |
// wdkn 256 | wdv 512 | wkr 64 | wpr 2048 ; total 10560.
__global__ __launch_bounds__(256)
void cvt_all(const float* __restrict__ x, const float* __restrict__ wcq,
             const float* __restrict__ wdqn, const float* __restrict__ wdqr,
             const float* __restrict__ wckv, const float* __restrict__ wdkn,
             const float* __restrict__ wdv, const float* __restrict__ wkr,
             const float* __restrict__ wpr,
             ushort_t* ox, ushort_t* owcq, ushort_t* owdqn, ushort_t* owdqr,
             ushort_t* owckv, ushort_t* owdkn, ushort_t* owdv, ushort_t* owkr,
             ushort_t* owpr) {
  int bid = blockIdx.x;
  const float* in; ushort_t* out;
  if (bid < 4096)      { in = x;    out = ox;    }
  else if (bid < 5632) { in = wcq;  out = owcq;  bid -= 4096; }
  else if (bid < 6400) { in = wdqn; out = owdqn; bid -= 5632; }
  else if (bid < 7168) { in = wdqr; out = owdqr; bid -= 6400; }
  else if (bid < 7680) { in = wckv; out = owckv; bid -= 7168; }
  else if (bid < 7936) { in = wdkn; out = owdkn; bid -= 7680; }
  else if (bid < 8448) { in = wdv;  out = owdv;  bid -= 7936; }
  else if (bid < 8512) { in = wkr;  out = owkr;  bid -= 8448; }
  else                 { in = wpr;  out = owpr;  bid -= 8512; }
  const long i = ((long)bid * 256 + threadIdx.x) * 8;
  float4 v0 = *(const float4*)(in + i);
  float4 v1 = *(const float4*)(in + i + 4);
  short8 o;
  o[0] = (short)f2bf(v0.x); o[1] = (short)f2bf(v0.y);
  o[2] = (short)f2bf(v0.z); o[3] = (short)f2bf(v0.w);
  o[4] = (short)f2bf(v1.x); o[5] = (short)f2bf(v1.y);
  o[6] = (short)f2bf(v1.z); o[7] = (short)f2bf(v1.w);
  *(short8*)(out + i) = o;
}

// ---------------- bf16 MFMA GEMM (single-output, fp32 or bf16 out) ----------------
template <int OUT_BF16>
__global__ __launch_bounds__(256)
void gemm_bt(const ushort_t* __restrict__ A, const ushort_t* __restrict__ B,
             void* __restrict__ Cv, int M, int N, int K) {
  __shared__ __align__(16) ushort_t As[128 * 64];
  __shared__ __align__(16) ushort_t Bs[128 * 64];
  const int tid = threadIdx.x;
  const int lane = tid & 63;
  const int wid = tid >> 6;
  const int m0 = blockIdx.y * 128;
  const int n0 = blockIdx.x * 128;
  const int wm = (wid >> 1) * 64;
  const int wn = (wid & 1) * 64;

  f32x4 acc[4][4];
#pragma unroll
  for (int m = 0; m < 4; ++m)
#pragma unroll
    for (int n = 0; n < 4; ++n) acc[m][n] = (f32x4){0.f, 0.f, 0.f, 0.f};

  const int ktiles = K >> 6;
  for (int kt = 0; kt < ktiles; ++kt) {
    const int k0 = kt << 6;
    __syncthreads();
#pragma unroll
    for (int i = 0; i < 4; ++i) {
      const int chunk = (i * 4 + wid) * 1024;
      const int o = chunk + lane * 16;
      const int row = o >> 7;
      const int cb = o & 127;
      const ushort_t* src = A + (long)(m0 + row) * K + (k0 + (cb >> 1));
      __builtin_amdgcn_global_load_lds((const __attribute__((address_space(1))) unsigned int*)src,
                                       (__attribute__((address_space(3))) unsigned int*)((char*)As + chunk),
                                       16, 0, 0);
    }
#pragma unroll
    for (int i = 0; i < 4; ++i) {
      const int chunk = (i * 4 + wid) * 1024;
      const int o = chunk + lane * 16;
      const int row = o >> 7;
      const int cb = o & 127;
      int brow = n0 + row;
      if (brow > N - 1) brow = N - 1;
      const ushort_t* src = B + (long)brow * K + (k0 + (cb >> 1));
      __builtin_amdgcn_global_load_lds((const __attribute__((address_space(1))) unsigned int*)src,
                                       (__attribute__((address_space(3))) unsigned int*)((char*)Bs + chunk),
                                       16, 0, 0);
    }
    __syncthreads();
#pragma unroll
    for (int kk = 0; kk < 2; ++kk) {
      const int kb = kk * 32 + ((lane >> 4) << 3);
      short8 a[4], b[4];
#pragma unroll
      for (int m = 0; m < 4; ++m)
        a[m] = *(const short8*)(As + (wm + m * 16 + (lane & 15)) * 64 + kb);
#pragma unroll
      for (int n = 0; n < 4; ++n)
        b[n] = *(const short8*)(Bs + (wn + n * 16 + (lane & 15)) * 64 + kb);
#pragma unroll
      for (int m = 0; m < 4; ++m)
#pragma unroll
        for (int n = 0; n < 4; ++n)
          acc[m][n] = __builtin_amdgcn_mfma_f32_16x16x32_bf16(a[m], b[n], acc[m][n], 0, 0, 0);
    }
  }
  const int rb = m0 + wm + ((lane >> 4) << 2);
  const int cbase = n0 + wn + (lane & 15);
#pragma unroll
  for (int m = 0; m < 4; ++m)
#pragma unroll
    for (int n = 0; n < 4; ++n) {
      const int c = cbase + n * 16;
      if (c < N) {
#pragma unroll
        for (int j = 0; j < 4; ++j) {
          const long r = rb + m * 16 + j;
          if (OUT_BF16)
            ((ushort_t*)Cv)[r * N + c] = f2bf(acc[m][n][j]);
          else
            ((float*)Cv)[r * N + c] = acc[m][n][j];
        }
      }
    }
}

// ---------------- merged 3-output GEMM (x-projections) ----------------
__global__ __launch_bounds__(256)
void gemm_bt3(const ushort_t* __restrict__ A,
              const ushort_t* __restrict__ B0, ushort_t* __restrict__ C0, int nb0, int N0,
              const ushort_t* __restrict__ B1, ushort_t* __restrict__ C1, int nb1, int N1,
              const ushort_t* __restrict__ B2, ushort_t* __restrict__ C2, int N2,
              int K) {
  __shared__ __align__(16) ushort_t As[128 * 64];
  __shared__ __align__(16) ushort_t Bs[128 * 64];
  int bx = blockIdx.x;
  const ushort_t* Bp; ushort_t* Cp; int N;
  if (bx < nb0)            { Bp = B0; Cp = C0; N = N0; }
  else if (bx < nb0 + nb1) { Bp = B1; Cp = C1; N = N1; bx -= nb0; }
  else                     { Bp = B2; Cp = C2; N = N2; bx -= nb0 + nb1; }
  const int tid = threadIdx.x;
  const int lane = tid & 63;
  const int wid = tid >> 6;
  const int m0 = blockIdx.y * 128;
  const int n0 = bx * 128;
  const int wm = (wid >> 1) * 64;
  const int wn = (wid & 1) * 64;

  f32x4 acc[4][4];
#pragma unroll
  for (int m = 0; m < 4; ++m)
#pragma unroll
    for (int n = 0; n < 4; ++n) acc[m][n] = (f32x4){0.f, 0.f, 0.f, 0.f};

  const int ktiles = K >> 6;
  for (int kt = 0; kt < ktiles; ++kt) {
    const int k0 = kt << 6;
    __syncthreads();
#pragma unroll
    for (int i = 0; i < 4; ++i) {
      const int chunk = (i * 4 + wid) * 1024;
      const int o = chunk + lane * 16;
      const int row = o >> 7;
      const int cb = o & 127;
      const ushort_t* src = A + (long)(m0 + row) * K + (k0 + (cb >> 1));
      __builtin_amdgcn_global_load_lds((const __attribute__((address_space(1))) unsigned int*)src,
                                       (__attribute__((address_space(3))) unsigned int*)((char*)As + chunk),
                                       16, 0, 0);
    }
#pragma unroll
    for (int i = 0; i < 4; ++i) {
      const int chunk = (i * 4 + wid) * 1024;
      const int o = chunk + lane * 16;
      const int row = o >> 7;
      const int cb = o & 127;
      int brow = n0 + row;
      if (brow > N - 1) brow = N - 1;
      const ushort_t* src = Bp + (long)brow * K + (k0 + (cb >> 1));
      __builtin_amdgcn_global_load_lds((const __attribute__((address_space(1))) unsigned int*)src,
                                       (__attribute__((address_space(3))) unsigned int*)((char*)Bs + chunk),
                                       16, 0, 0);
    }
    __syncthreads();
#pragma unroll
    for (int kk = 0; kk < 2; ++kk) {
      const int kb = kk * 32 + ((lane >> 4) << 3);
      short8 a[4], b[4];
#pragma unroll
      for (int m = 0; m < 4; ++m)
        a[m] = *(const short8*)(As + (wm + m * 16 + (lane & 15)) * 64 + kb);
#pragma unroll
      for (int n = 0; n < 4; ++n)
        b[n] = *(const short8*)(Bs + (wn + n * 16 + (lane & 15)) * 64 + kb);
#pragma unroll
      for (int m = 0; m < 4; ++m)
#pragma unroll
        for (int n = 0; n < 4; ++n)
          acc[m][n] = __builtin_amdgcn_mfma_f32_16x16x32_bf16(a[m], b[n], acc[m][n], 0, 0, 0);
    }
  }
  const int rb = m0 + wm + ((lane >> 4) << 2);
  const int cbase = n0 + wn + (lane & 15);
#pragma unroll
  for (int m = 0; m < 4; ++m)
#pragma unroll
    for (int n = 0; n < 4; ++n) {
      const int c = cbase + n * 16;
      if (c < N) {
#pragma unroll
        for (int j = 0; j < 4; ++j) {
          const long r = rb + m * 16 + j;
          Cp[r * N + c] = f2bf(acc[m][n][j]);
        }
      }
    }
}

// ---------------- merged 4-output GEMM (q & kv projections; per-segment A,K) ----------------
__global__ __launch_bounds__(256)
void gemm_qkv(const ushort_t* __restrict__ nq, const ushort_t* __restrict__ nkv,
              const ushort_t* __restrict__ wdqn, ushort_t* __restrict__ qnope,
              const ushort_t* __restrict__ wdqr, ushort_t* __restrict__ qr,
              const ushort_t* __restrict__ wdkn, ushort_t* __restrict__ knope,
              const ushort_t* __restrict__ wdv, ushort_t* __restrict__ vt) {
  __shared__ __align__(16) ushort_t S[16384];  // As | Bs ; reused 32KB for transpose epilogue
  ushort_t* As = S;
  ushort_t* Bs = S + 8192;
  int bx = blockIdx.x;
  const ushort_t* Ap; const ushort_t* Bp; ushort_t* Cp; int N, K; bool tv = false;
  if (bx < 8)       { Ap = nq;  K = 1536; Bp = wdqn; Cp = qnope; N = 1024; }
  else if (bx < 16) { Ap = nq;  K = 1536; Bp = wdqr; Cp = qr;    N = 1024; bx -= 8; }
  else if (bx < 24) { Ap = nkv; K = 512;  Bp = wdkn; Cp = knope; N = 1024; bx -= 16; }
  else              { Ap = nkv; K = 512;  Bp = wdv;  Cp = vt;    N = 2048; bx -= 24; tv = true; }
  const int tid = threadIdx.x;
  const int lane = tid & 63;
  const int wid = tid >> 6;
  const int m0 = blockIdx.y * 128;
  const int n0 = bx * 128;
  const int wm = (wid >> 1) * 64;
  const int wn = (wid & 1) * 64;

  f32x4 acc[4][4];
#pragma unroll
  for (int m = 0; m < 4; ++m)
#pragma unroll
    for (int n = 0; n < 4; ++n) acc[m][n] = (f32x4){0.f, 0.f, 0.f, 0.f};

  const int ktiles = K >> 6;
  for (int kt = 0; kt < ktiles; ++kt) {
    const int k0 = kt << 6;
    __syncthreads();
#pragma unroll
    for (int i = 0; i < 4; ++i) {
      const int chunk = (i * 4 + wid) * 1024;
      const int o = chunk + lane * 16;
      const int row = o >> 7;
      const int cb = o & 127;
      const ushort_t* src = Ap + (long)(m0 + row) * K + (k0 + (cb >> 1));
      __builtin_amdgcn_global_load_lds((const __attribute__((address_space(1))) unsigned int*)src,
                                       (__attribute__((address_space(3))) unsigned int*)((char*)As + chunk),
                                       16, 0, 0);
    }
#pragma unroll
    for (int i = 0; i < 4; ++i) {
      const int chunk = (i * 4 + wid) * 1024;
      const int o = chunk + lane * 16;
      const int row = o >> 7;
      const int cb = o & 127;
      const ushort_t* src = Bp + (long)(n0 + row) * K + (k0 + (cb >> 1));
      __builtin_amdgcn_global_load_lds((const __attribute__((address_space(1))) unsigned int*)src,
                                       (__attribute__((address_space(3))) unsigned int*)((char*)Bs + chunk),
                                       16, 0, 0);
    }
    __syncthreads();
#pragma unroll
    for (int kk = 0; kk < 2; ++kk) {
      const int kb = kk * 32 + ((lane >> 4) << 3);
      short8 a[4], b[4];
#pragma unroll
      for (int m = 0; m < 4; ++m)
        a[m] = *(const short8*)(As + (wm + m * 16 + (lane & 15)) * 64 + kb);
#pragma unroll
      for (int n = 0; n < 4; ++n)
        b[n] = *(const short8*)(Bs + (wn + n * 16 + (lane & 15)) * 64 + kb);
#pragma unroll
      for (int m = 0; m < 4; ++m)
#pragma unroll
        for (int n = 0; n < 4; ++n)
          acc[m][n] = __builtin_amdgcn_mfma_f32_16x16x32_bf16(a[m], b[n], acc[m][n], 0, 0, 0);
    }
  }
  if (tv) {
    __syncthreads();
    const int lrb = wm + ((lane >> 4) << 2);
    const int ldb = wn + (lane & 15);
#pragma unroll
    for (int m = 0; m < 4; ++m)
#pragma unroll
      for (int n = 0; n < 4; ++n) {
        const int ld = ldb + n * 16;
#pragma unroll
        for (int j = 0; j < 4; ++j) {
          const int lr = lrb + m * 16 + j;
          *(ushort_t*)((char*)S + lr * 256 + ((2 * ld) ^ ((lr & 15) << 4))) = f2bf(acc[m][n][j]);
        }
      }
    __syncthreads();
    const int b = m0 >> 11;
    const int s0 = m0 & 2047;
    const int bh = b * 16 + bx;
    const int d = tid & 127;
    const int sh = (tid >> 7) * 64;
#pragma unroll
    for (int i = 0; i < 8; ++i) {
      const int sbase = sh + i * 8;
      short8 val;
#pragma unroll
      for (int j = 0; j < 8; ++j) {
        const int s = sbase + j;
        val[j] = (short)*(const ushort_t*)((const char*)S + s * 256 + ((2 * d) ^ ((s & 15) << 4)));
      }
      *(short8*)(Cp + ((long)bh * 128 + d) * 2048 + s0 + sbase) = val;
    }
    return;
  }
  const int rb = m0 + wm + ((lane >> 4) << 2);
  const int cbase = n0 + wn + (lane & 15);
#pragma unroll
  for (int m = 0; m < 4; ++m)
#pragma unroll
    for (int n = 0; n < 4; ++n) {
      const int c = cbase + n * 16;
#pragma unroll
      for (int j = 0; j < 4; ++j) {
        const long r = rb + m * 16 + j;
        Cp[r * N + c] = f2bf(acc[m][n][j]);
      }
    }
}

// ---------------- rmsnorm + rope_kraw merged ----------------
__device__ __forceinline__ void rms_body(const ushort_t* x, const float* w,
                                         ushort_t* out, int R, float* warr) {
  const int tid = threadIdx.x;
  float ss = 0.f;
  for (int i = tid; i < R; i += 256) { float v = bf2f(x[i]); ss += v * v; }
#pragma unroll
  for (int off = 32; off; off >>= 1) ss += __shfl_xor(ss, off);
  if ((tid & 63) == 0) warr[tid >> 6] = ss;
  __syncthreads();
  const float tot = warr[0] + warr[1] + warr[2] + warr[3];
  const float rs = rsqrtf(tot / (float)R + 1e-6f);
  for (int i = tid; i < R; i += 256) out[i] = f2bf(bf2f(x[i]) * rs * w[i]);
}

__device__ __forceinline__ void rope_body(const ushort_t* in, ushort_t* out,
                                          const float* fc, const float* fs,
                                          int heads, int bid) {
  const int idx = bid * 256 + threadIdx.x;
  const int i = idx & 31;
  const int rest = idx >> 5;
  const int hh = rest % heads;
  const int row = rest / heads;
  const int srow = row & 2047;
  const float c = fc[srow * 32 + i];
  const float s = fs[srow * 32 + i];
  const long base = (long)row * heads * 64 + hh * 64 + 2 * i;
  const float x0 = bf2f(in[base]);
  const float x1 = bf2f(in[base + 1]);
  out[base] = f2bf(x0 * c - x1 * s);
  out[base + 1] = f2bf(x0 * s + x1 * c);
}

__global__ __launch_bounds__(256)
void rms_rope(const ushort_t* __restrict__ ckv, const float* __restrict__ kvnw,
              ushort_t* __restrict__ nkv,
              const ushort_t* __restrict__ cq, const float* __restrict__ qnw,
              ushort_t* __restrict__ nq,
              const ushort_t* __restrict__ kraw, ushort_t* __restrict__ qrs,
              const float* __restrict__ fc, const float* __restrict__ fs) {
  __shared__ float warr[4];
  const int bid = blockIdx.x;
  if (bid < 4096) rms_body(ckv + (long)bid * 512, kvnw, nkv + (long)bid * 512, 512, warr);
  else if (bid < 8192) {
    const long row = bid - 4096;
    rms_body(cq + row * 1536, qnw, nq + row * 1536, 1536, warr);
  } else {
    rope_body(kraw, qrs, fc, fs, 1, bid - 8192);
  }
}

__global__ __launch_bounds__(256)
void rope_qr(const ushort_t* __restrict__ qr, ushort_t* __restrict__ krope,
             const float* __restrict__ fc, const float* __restrict__ fs) {
  rope_body(qr, krope, fc, fs, 16, blockIdx.x);
}

// ---------------- MFMA flash attention v8 (round-15 measured: 95.8 us) ----------------
// 8-wave block, 2 q-tiles {pair, 15-pair}, 128-key tiles -> 17 phases/block.
// Skew pipeline QK(t+1) ∥ softmax(t), 1 barrier/tile. LDS 144KB.
__global__ __launch_bounds__(512)
void attn_mfma(const ushort_t* __restrict__ qn, const ushort_t* __restrict__ qrs,
               const ushort_t* __restrict__ kn, const ushort_t* __restrict__ kr,
               const ushort_t* __restrict__ vt, ushort_t* __restrict__ out) {
  __shared__ __align__(16) ushort_t Ks[2][16384];   // [128 k][128 d], rows 256B, swizzled
  __shared__ __align__(16) ushort_t Vts[2][16384];  // [128 d][128 s], rows 256B, swizzled
  __shared__ __align__(16) ushort_t Ps[8192];       // per-wave [16 q][64 k] = 2048B x 8 waves
  const int tid = threadIdx.x, lane = tid & 63, wid = tid >> 6;
  const int g = lane >> 4, lq = lane & 15;
  const int bh = blockIdx.x, b = bh >> 4, h = bh & 15;
  const float scale = 0.08838834764831845f;  // 1/sqrt(128)
  char* Pbase = (char*)Ps + wid * 2048;

  auto stageK = [&](int bsel, int kt) {
    const int k0s = kt * 128;
#pragma unroll
    for (int i = 0; i < 4; ++i) {
      const int cc = wid * 4 + i;
      const int o = cc * 1024 + lane * 16;
      const int row = o >> 8;
      const int dK = ((o & 255) ^ ((row & 7) << 4)) >> 1;
      const long krow = (long)b * 2048 + k0s + row;
      const ushort_t* srcK = (dK < 64) ? (kn + krow * 1024 + h * 64 + dK)
                                       : (kr + krow * 1024 + h * 64 + (dK - 64));
      __builtin_amdgcn_global_load_lds((const __attribute__((address_space(1))) unsigned int*)srcK,
          (__attribute__((address_space(3))) unsigned int*)((char*)Ks[bsel] + cc * 1024), 16, 0, 0);
    }
  };
  auto stageV = [&](int bsel, int kt) {
    const int k0s = kt * 128;
#pragma unroll
    for (int i = 0; i < 4; ++i) {
      const int cc = wid * 4 + i;
      const int o = cc * 1024 + lane * 16;
      const int dr = o >> 8;
      const int se = ((o & 255) ^ ((dr & 7) << 4)) >> 1;
      const ushort_t* srcV = vt + ((long)bh * 128 + dr) * 2048 + k0s + se;
      __builtin_amdgcn_global_load_lds((const __attribute__((address_space(1))) unsigned int*)srcV,
          (__attribute__((address_space(3))) unsigned int*)((char*)Vts[bsel] + cc * 1024), 16, 0, 0);
    }
  };

  const int pair = blockIdx.y;
  for (int half = 0; half < 2; ++half) {
    const int tq = half ? (15 - pair) : pair;  // 128-row q-tile index
    const int q0 = tq * 128;
    const int qw0 = q0 + wid * 16;
    short8 aq[4];
    {
      const long grow = (long)b * 2048 + qw0 + lq;
#pragma unroll
      for (int ks = 0; ks < 4; ++ks) {
        const int d = ks * 32 + g * 8;
        const ushort_t* src = (d < 64) ? (qn + grow * 1024 + h * 64 + d)
                                       : (qrs + grow * 64 + (d - 64));
        aq[ks] = *(const short8*)src;
      }
    }
    f32x4 oacc[8];
#pragma unroll
    for (int n = 0; n < 8; ++n) oacc[n] = (f32x4){0.f, 0.f, 0.f, 0.f};
    float sm[4] = {-3e38f, -3e38f, -3e38f, -3e38f};
    float sl[4] = {0.f, 0.f, 0.f, 0.f};

    auto qk = [&](f32x4 (&sacc)[8], int u) {
#pragma unroll
      for (int n = 0; n < 8; ++n) sacc[n] = (f32x4){0.f, 0.f, 0.f, 0.f};
      const ushort_t* Kbuf = Ks[u & 1];
      __builtin_amdgcn_s_setprio(1);
#pragma unroll
      for (int ks = 0; ks < 4; ++ks) {
        const int x = ks * 64 + g * 16;
#pragma unroll
        for (int n = 0; n < 8; ++n) {
          const int kl = n * 16 + lq;
          short8 bk = *(const short8*)((const char*)Kbuf + kl * 256 + (x ^ ((kl & 7) << 4)));
          sacc[n] = __builtin_amdgcn_mfma_f32_16x16x32_bf16(aq[ks], bk, sacc[n], 0, 0, 0);
        }
      }
      __builtin_amdgcn_s_setprio(0);
    };
    auto process = [&](f32x4 (&sacc)[8], int u) {
      const int k0 = u * 128;
      if (k0 + 127 > qw0) {  // causal mask (wave-uniform condition)
#pragma unroll
        for (int n = 0; n < 8; ++n) {
          const int key = k0 + n * 16 + lq;
#pragma unroll
          for (int j = 0; j < 4; ++j) {
            const int qrow = qw0 + g * 4 + j;
            if (key > qrow) sacc[n][j] = -3e38f;
          }
        }
      }
      float tmax[4];
#pragma unroll
      for (int j = 0; j < 4; ++j) {
        float t0 = fmaxf(fmaxf(sacc[0][j], sacc[1][j]), fmaxf(sacc[2][j], sacc[3][j]));
        float t1 = fmaxf(fmaxf(sacc[4][j], sacc[5][j]), fmaxf(sacc[6][j], sacc[7][j]));
        tmax[j] = fmaxf(t0, t1);
      }
#pragma unroll
      for (int off = 1; off < 16; off <<= 1)
#pragma unroll
        for (int j = 0; j < 4; ++j) tmax[j] = fmaxf(tmax[j], __shfl_xor(tmax[j], off));
      bool need = false;
#pragma unroll
      for (int j = 0; j < 4; ++j) {
        tmax[j] *= scale;
        need = need || (tmax[j] > sm[j] + 8.f);
      }
      if (__any(need)) {
#pragma unroll
        for (int j = 0; j < 4; ++j) {
          const float mn = fmaxf(sm[j], tmax[j]);
          const float fr = __expf(sm[j] - mn);
          sm[j] = mn;
          sl[j] *= fr;
#pragma unroll
          for (int n = 0; n < 8; ++n) oacc[n][j] *= fr;
        }
      }
      f32x4 p[8];
#pragma unroll
      for (int n = 0; n < 8; ++n)
#pragma unroll
        for (int j = 0; j < 4; ++j)
          p[n][j] = __expf(__builtin_fmaf(sacc[n][j], scale, -sm[j]));
      float psum[4];
#pragma unroll
      for (int j = 0; j < 4; ++j) {
        psum[j] = ((p[0][j] + p[1][j]) + (p[2][j] + p[3][j])) +
                  ((p[4][j] + p[5][j]) + (p[6][j] + p[7][j]));
      }
#pragma unroll
      for (int off = 1; off < 16; off <<= 1)
#pragma unroll
        for (int j = 0; j < 4; ++j) psum[j] += __shfl_xor(psum[j], off);
#pragma unroll
      for (int j = 0; j < 4; ++j) sl[j] += psum[j];
      const ushort_t* Vbuf = Vts[u & 1];
#pragma unroll
      for (int hh = 0; hh < 2; ++hh) {
#pragma unroll
        for (int nn = 0; nn < 4; ++nn) {
          const int n = hh * 4 + nn;
          const int col2 = (nn * 16 + lq) * 2;
#pragma unroll
          for (int j = 0; j < 4; ++j) {
            const int row = g * 4 + j;
            *(ushort_t*)(Pbase + row * 128 + (col2 ^ ((row & 7) << 4))) = f2bf(p[n][j]);
          }
        }
        __builtin_amdgcn_s_setprio(1);
#pragma unroll
        for (int ks2 = 0; ks2 < 2; ++ks2) {
          const int x = ks2 * 64 + g * 16;
          short8 pa = *(const short8*)(Pbase + lq * 128 + (x ^ ((lq & 7) << 4)));
          const int xv = (hh * 2 + ks2) * 64 + g * 16;
#pragma unroll
          for (int nd = 0; nd < 8; ++nd) {
            const int dl = nd * 16 + lq;
            short8 vb = *(const short8*)((const char*)Vbuf + dl * 256 + (xv ^ ((dl & 7) << 4)));
            oacc[nd] = __builtin_amdgcn_mfma_f32_16x16x32_bf16(pa, vb, oacc[nd], 0, 0, 0);
          }
        }
        __builtin_amdgcn_s_setprio(0);
      }
    };

    const int kmax = tq + 1;  // 128-key tiles (may be odd)
    f32x4 saccA[8], saccB[8];
    // prologue
    stageK(0, 0); stageV(0, 0);
    if (kmax > 1) stageK(1, 1);
    asm volatile("s_waitcnt vmcnt(0)" ::: "memory");
    __builtin_amdgcn_s_barrier();
    __builtin_amdgcn_sched_barrier(0);
    qk(saccA, 0);
    int u = 0;
    for (; u + 1 < kmax; u += 2) {
      // ---- phase even: tile u ----
      if (u + 2 < kmax) stageK(0, u + 2);
      stageV(1, u + 1);
      qk(saccB, u + 1);      // MFMA reads Ks[1] — ∥ softmax below
      process(saccA, u);     // VALU + PV reads Vts[0]
      asm volatile("s_waitcnt vmcnt(0)" ::: "memory");
      __builtin_amdgcn_s_barrier();
      __builtin_amdgcn_sched_barrier(0);
      // ---- phase odd: tile u+1 ----
      if (u + 3 < kmax) stageK(1, u + 3);
      if (u + 2 < kmax) stageV(0, u + 2);
      if (u + 2 < kmax) qk(saccA, u + 2);
      process(saccB, u + 1);
      asm volatile("s_waitcnt vmcnt(0)" ::: "memory");
      __builtin_amdgcn_s_barrier();
      __builtin_amdgcn_sched_barrier(0);
    }
    if (u < kmax) {  // odd kmax: final tile (even parity -> saccA, Vts[0])
      process(saccA, u);
      __builtin_amdgcn_s_barrier();  // all reads done before next half restages
    }
    // ---- epilogue for this q-tile ----
    float inv[4];
#pragma unroll
    for (int j = 0; j < 4; ++j) inv[j] = 1.f / sl[j];
#pragma unroll
    for (int nd = 0; nd < 8; ++nd) {
      const int d = nd * 16 + lq;
#pragma unroll
      for (int j = 0; j < 4; ++j) {
        const long row = (long)b * 2048 + qw0 + g * 4 + j;
        out[row * 2048 + h * 128 + d] = f2bf(oacc[nd][j] * inv[j]);
      }
    }
  }
}

// ---------------- launch ----------------
// Workspace: EXACTLY 101,711,872 B (round-3-proven bound).
extern "C" void kernel_launch(void* const* d_in, const int* in_sizes, int n_in,
                              void* d_out, int out_size, void* d_ws, size_t ws_size,
                              hipStream_t stream) {
  const float* x      = (const float*)d_in[0];
  const float* fcos   = (const float*)d_in[1];
  const float* fsin   = (const float*)d_in[2];
  const float* w_cq   = (const float*)d_in[3];
  const float* w_dqn  = (const float*)d_in[4];
  const float* w_dqr  = (const float*)d_in[5];
  const float* w_ckv  = (const float*)d_in[6];
  const float* w_dkn  = (const float*)d_in[7];
  const float* w_dv   = (const float*)d_in[8];
  const float* w_kr   = (const float*)d_in[9];
  const float* w_proj = (const float*)d_in[10];
  const float* qnw    = (const float*)d_in[11];
  const float* kvnw   = (const float*)d_in[12];
  float* out = (float*)d_out;

  char* ws = (char*)d_ws;
  ushort_t* x_bf     = (ushort_t*)(ws + 0);
  ushort_t* wcq_bf   = (ushort_t*)(ws + 16777216);  // dead after step 2
  ushort_t* qrs_bf   = (ushort_t*)(ws + 16777216);  //   written step 3, read step 6
  ushort_t* wdqn_bf  = (ushort_t*)(ws + 23068672);
  ushort_t* wdqr_bf  = (ushort_t*)(ws + 26214400);
  ushort_t* wckv_bf  = (ushort_t*)(ws + 29360128);
  ushort_t* wdkn_bf  = (ushort_t*)(ws + 31457280);
  ushort_t* wdv_bf   = (ushort_t*)(ws + 32505856);
  ushort_t* wpr_bf   = (ushort_t*)(ws + 34603008);
  ushort_t* cq_bf    = (ushort_t*)(ws + 42991616);  // CQ region
  ushort_t* krope_bf = (ushort_t*)(ws + 42991616);  //   after cq dead (rope_qr, step 5)
  ushort_t* ckv_bf   = (ushort_t*)(ws + 55574528);  // CKVNQ region
  ushort_t* nq_bf    = (ushort_t*)(ws + 59768832);
  ushort_t* attn_bf  = (ushort_t*)(ws + 55574528);  //   after ckv/nq dead (step 6)
  ushort_t* nkv_bf   = (ushort_t*)(ws + 72351744);
  ushort_t* qnope_bf = (ushort_t*)(ws + 76546048);  // QNOPE region
  ushort_t* kraw_bf  = (ushort_t*)(ws + 76546048);  //   before qnope written (step 4)
  ushort_t* qr_bf    = (ushort_t*)(ws + 0);         // X region, after x_bf dead
  ushort_t* knope_bf = (ushort_t*)(ws + 8388608);
  ushort_t* wkr_bf   = (ushort_t*)(ws + 84934656);  // V region (dead after step 2)
  ushort_t* vt_bf    = (ushort_t*)(ws + 84934656);  //   vt written step 4

  // 1. all converts (8 elems/thread)
  cvt_all<<<10560, 256, 0, stream>>>(x, w_cq, w_dqn, w_dqr, w_ckv, w_dkn, w_dv, w_kr, w_proj,
                                     x_bf, wcq_bf, wdqn_bf, wdqr_bf, wckv_bf, wdkn_bf,
                                     wdv_bf, wkr_bf, wpr_bf);
  // 2. merged x-projections: [ckv 4 | cq 12 | kraw 1] blocks, K=2048
  gemm_bt3<<<dim3(17, 32), 256, 0, stream>>>(x_bf,
                                             wckv_bf, ckv_bf, 4, 512,
                                             wcq_bf, cq_bf, 12, 1536,
                                             wkr_bf, kraw_bf, 64, 2048);
  // 3. rmsnorms + rope kraw->qrs
  rms_rope<<<8704, 256, 0, stream>>>(ckv_bf, kvnw, nkv_bf, cq_bf, qnw, nq_bf,
                                     kraw_bf, qrs_bf, fcos, fsin);
  // 4. merged q+kv projections: [qnope 8 | qr 8 | knope 8 | vt 16]
  gemm_qkv<<<dim3(40, 32), 256, 0, stream>>>(nq_bf, nkv_bf,
                                             wdqn_bf, qnope_bf,
                                             wdqr_bf, qr_bf,
                                             wdkn_bf, knope_bf,
                                             wdv_bf, vt_bf);
  // 5. rope qr -> krope
  rope_qr<<<8192, 256, 0, stream>>>(qr_bf, krope_bf, fcos, fsin);
  // 6. MFMA flash attention v8 (round-15 structure, 95.8 us)
  attn_mfma<<<dim3(32, 8), 512, 0, stream>>>(qnope_bf, qrs_bf, knope_bf, krope_bf, vt_bf, attn_bf);
  // 7. final projection (fp32 out)
  gemm_bt<0><<<dim3(16, 32), 256, 0, stream>>>(attn_bf, wpr_bf, out, 4096, 2048, 2048);
}

// Round 18
// 332.022 us; speedup vs baseline: 1.0427x; 1.0184x over previous
//
#include <hip/hip_runtime.h>

typedef __attribute__((ext_vector_type(4))) float f32x4;
typedef __attribute__((ext_vector_type(8))) short short8;
typedef unsigned short ushort_t;

__device__ __forceinline__ float bf2f(ushort_t u) {
  unsigned int i = ((unsigned int)u) << 16;
  return __builtin_bit_cast(float, i);
}
__device__ __forceinline__ ushort_t f2bf(float f) {
  unsigned int x = __builtin_bit_cast(unsigned int, f);
  unsigned int r = (x + 0x7FFFu + ((x >> 16) & 1u)) >> 16;
  return (ushort_t)r;
}

// ---------------- fused fp32 -> bf16 convert: all 9 inputs, 8 elems/thread ----------------
__global__ __launch_bounds__(256)
void cvt_all(const float* __restrict__ x, const float* __restrict__ wcq,
             const float* __restrict__ wdqn, const float* __restrict__ wdqr,
             const float* __restrict__ wckv, const float* __restrict__ wdkn,
             const float* __restrict__ wdv, const float* __restrict__ wkr,
             const float* __restrict__ wpr,
             ushort_t* ox, ushort_t* owcq, ushort_t* owdqn, ushort_t* owdqr,
             ushort_t* owckv, ushort_t* owdkn, ushort_t* owdv, ushort_t* owkr,
             ushort_t* owpr) {
  int bid = blockIdx.x;
  const float* in; ushort_t* out;
  if (bid < 4096)      { in = x;    out = ox;    }
  else if (bid < 5632) { in = wcq;  out = owcq;  bid -= 4096; }
  else if (bid < 6400) { in = wdqn; out = owdqn; bid -= 5632; }
  else if (bid < 7168) { in = wdqr; out = owdqr; bid -= 6400; }
  else if (bid < 7680) { in = wckv; out = owckv; bid -= 7168; }
  else if (bid < 7936) { in = wdkn; out = owdkn; bid -= 7680; }
  else if (bid < 8448) { in = wdv;  out = owdv;  bid -= 7936; }
  else if (bid < 8512) { in = wkr;  out = owkr;  bid -= 8448; }
  else                 { in = wpr;  out = owpr;  bid -= 8512; }
  const long i = ((long)bid * 256 + threadIdx.x) * 8;
  float4 v0 = *(const float4*)(in + i);
  float4 v1 = *(const float4*)(in + i + 4);
  short8 o;
  o[0] = (short)f2bf(v0.x); o[1] = (short)f2bf(v0.y);
  o[2] = (short)f2bf(v0.z); o[3] = (short)f2bf(v0.w);
  o[4] = (short)f2bf(v1.x); o[5] = (short)f2bf(v1.y);
  o[6] = (short)f2bf(v1.z); o[7] = (short)f2bf(v1.w);
  *(short8*)(out + i) = o;
}

// ---------------- bf16 MFMA GEMM (single-output, fp32 or bf16 out) ----------------
template <int OUT_BF16>
__global__ __launch_bounds__(256)
void gemm_bt(const ushort_t* __restrict__ A, const ushort_t* __restrict__ B,
             void* __restrict__ Cv, int M, int N, int K) {
  __shared__ __align__(16) ushort_t As[128 * 64];
  __shared__ __align__(16) ushort_t Bs[128 * 64];
  const int tid = threadIdx.x;
  const int lane = tid & 63;
  const int wid = tid >> 6;
  const int m0 = blockIdx.y * 128;
  const int n0 = blockIdx.x * 128;
  const int wm = (wid >> 1) * 64;
  const int wn = (wid & 1) * 64;

  f32x4 acc[4][4];
#pragma unroll
  for (int m = 0; m < 4; ++m)
#pragma unroll
    for (int n = 0; n < 4; ++n) acc[m][n] = (f32x4){0.f, 0.f, 0.f, 0.f};

  const int ktiles = K >> 6;
  for (int kt = 0; kt < ktiles; ++kt) {
    const int k0 = kt << 6;
    __syncthreads();
#pragma unroll
    for (int i = 0; i < 4; ++i) {
      const int chunk = (i * 4 + wid) * 1024;
      const int o = chunk + lane * 16;
      const int row = o >> 7;
      const int cb = o & 127;
      const ushort_t* src = A + (long)(m0 + row) * K + (k0 + (cb >> 1));
      __builtin_amdgcn_global_load_lds((const __attribute__((address_space(1))) unsigned int*)src,
                                       (__attribute__((address_space(3))) unsigned int*)((char*)As + chunk),
                                       16, 0, 0);
    }
#pragma unroll
    for (int i = 0; i < 4; ++i) {
      const int chunk = (i * 4 + wid) * 1024;
      const int o = chunk + lane * 16;
      const int row = o >> 7;
      const int cb = o & 127;
      int brow = n0 + row;
      if (brow > N - 1) brow = N - 1;
      const ushort_t* src = B + (long)brow * K + (k0 + (cb >> 1));
      __builtin_amdgcn_global_load_lds((const __attribute__((address_space(1))) unsigned int*)src,
                                       (__attribute__((address_space(3))) unsigned int*)((char*)Bs + chunk),
                                       16, 0, 0);
    }
    __syncthreads();
#pragma unroll
    for (int kk = 0; kk < 2; ++kk) {
      const int kb = kk * 32 + ((lane >> 4) << 3);
      short8 a[4], b[4];
#pragma unroll
      for (int m = 0; m < 4; ++m)
        a[m] = *(const short8*)(As + (wm + m * 16 + (lane & 15)) * 64 + kb);
#pragma unroll
      for (int n = 0; n < 4; ++n)
        b[n] = *(const short8*)(Bs + (wn + n * 16 + (lane & 15)) * 64 + kb);
#pragma unroll
      for (int m = 0; m < 4; ++m)
#pragma unroll
        for (int n = 0; n < 4; ++n)
          acc[m][n] = __builtin_amdgcn_mfma_f32_16x16x32_bf16(a[m], b[n], acc[m][n], 0, 0, 0);
    }
  }
  const int rb = m0 + wm + ((lane >> 4) << 2);
  const int cbase = n0 + wn + (lane & 15);
#pragma unroll
  for (int m = 0; m < 4; ++m)
#pragma unroll
    for (int n = 0; n < 4; ++n) {
      const int c = cbase + n * 16;
      if (c < N) {
#pragma unroll
        for (int j = 0; j < 4; ++j) {
          const long r = rb + m * 16 + j;
          if (OUT_BF16)
            ((ushort_t*)Cv)[r * N + c] = f2bf(acc[m][n][j]);
          else
            ((float*)Cv)[r * N + c] = acc[m][n][j];
        }
      }
    }
}

// ---------------- merged 3-output GEMM (x-projections) ----------------
__global__ __launch_bounds__(256)
void gemm_bt3(const ushort_t* __restrict__ A,
              const ushort_t* __restrict__ B0, ushort_t* __restrict__ C0, int nb0, int N0,
              const ushort_t* __restrict__ B1, ushort_t* __restrict__ C1, int nb1, int N1,
              const ushort_t* __restrict__ B2, ushort_t* __restrict__ C2, int N2,
              int K) {
  __shared__ __align__(16) ushort_t As[128 * 64];
  __shared__ __align__(16) ushort_t Bs[128 * 64];
  int bx = blockIdx.x;
  const ushort_t* Bp; ushort_t* Cp; int N;
  if (bx < nb0)            { Bp = B0; Cp = C0; N = N0; }
  else if (bx < nb0 + nb1) { Bp = B1; Cp = C1; N = N1; bx -= nb0; }
  else                     { Bp = B2; Cp = C2; N = N2; bx -= nb0 + nb1; }
  const int tid = threadIdx.x;
  const int lane = tid & 63;
  const int wid = tid >> 6;
  const int m0 = blockIdx.y * 128;
  const int n0 = bx * 128;
  const int wm = (wid >> 1) * 64;
  const int wn = (wid & 1) * 64;

  f32x4 acc[4][4];
#pragma unroll
  for (int m = 0; m < 4; ++m)
#pragma unroll
    for (int n = 0; n < 4; ++n) acc[m][n] = (f32x4){0.f, 0.f, 0.f, 0.f};

  const int ktiles = K >> 6;
  for (int kt = 0; kt < ktiles; ++kt) {
    const int k0 = kt << 6;
    __syncthreads();
#pragma unroll
    for (int i = 0; i < 4; ++i) {
      const int chunk = (i * 4 + wid) * 1024;
      const int o = chunk + lane * 16;
      const int row = o >> 7;
      const int cb = o & 127;
      const ushort_t* src = A + (long)(m0 + row) * K + (k0 + (cb >> 1));
      __builtin_amdgcn_global_load_lds((const __attribute__((address_space(1))) unsigned int*)src,
                                       (__attribute__((address_space(3))) unsigned int*)((char*)As + chunk),
                                       16, 0, 0);
    }
#pragma unroll
    for (int i = 0; i < 4; ++i) {
      const int chunk = (i * 4 + wid) * 1024;
      const int o = chunk + lane * 16;
      const int row = o >> 7;
      const int cb = o & 127;
      int brow = n0 + row;
      if (brow > N - 1) brow = N - 1;
      const ushort_t* src = Bp + (long)brow * K + (k0 + (cb >> 1));
      __builtin_amdgcn_global_load_lds((const __attribute__((address_space(1))) unsigned int*)src,
                                       (__attribute__((address_space(3))) unsigned int*)((char*)Bs + chunk),
                                       16, 0, 0);
    }
    __syncthreads();
#pragma unroll
    for (int kk = 0; kk < 2; ++kk) {
      const int kb = kk * 32 + ((lane >> 4) << 3);
      short8 a[4], b[4];
#pragma unroll
      for (int m = 0; m < 4; ++m)
        a[m] = *(const short8*)(As + (wm + m * 16 + (lane & 15)) * 64 + kb);
#pragma unroll
      for (int n = 0; n < 4; ++n)
        b[n] = *(const short8*)(Bs + (wn + n * 16 + (lane & 15)) * 64 + kb);
#pragma unroll
      for (int m = 0; m < 4; ++m)
#pragma unroll
        for (int n = 0; n < 4; ++n)
          acc[m][n] = __builtin_amdgcn_mfma_f32_16x16x32_bf16(a[m], b[n], acc[m][n], 0, 0, 0);
    }
  }
  const int rb = m0 + wm + ((lane >> 4) << 2);
  const int cbase = n0 + wn + (lane & 15);
#pragma unroll
  for (int m = 0; m < 4; ++m)
#pragma unroll
    for (int n = 0; n < 4; ++n) {
      const int c = cbase + n * 16;
      if (c < N) {
#pragma unroll
        for (int j = 0; j < 4; ++j) {
          const long r = rb + m * 16 + j;
          Cp[r * N + c] = f2bf(acc[m][n][j]);
        }
      }
    }
}

// ---------------- merged 4-output GEMM (q & kv projections; per-segment A,K) ----------------
__global__ __launch_bounds__(256)
void gemm_qkv(const ushort_t* __restrict__ nq, const ushort_t* __restrict__ nkv,
              const ushort_t* __restrict__ wdqn, ushort_t* __restrict__ qnope,
              const ushort_t* __restrict__ wdqr, ushort_t* __restrict__ qr,
              const ushort_t* __restrict__ wdkn, ushort_t* __restrict__ knope,
              const ushort_t* __restrict__ wdv, ushort_t* __restrict__ vt) {
  __shared__ __align__(16) ushort_t S[16384];  // As | Bs ; reused 32KB for transpose epilogue
  ushort_t* As = S;
  ushort_t* Bs = S + 8192;
  int bx = blockIdx.x;
  const ushort_t* Ap; const ushort_t* Bp; ushort_t* Cp; int N, K; bool tv = false;
  if (bx < 8)       { Ap = nq;  K = 1536; Bp = wdqn; Cp = qnope; N = 1024; }
  else if (bx < 16) { Ap = nq;  K = 1536; Bp = wdqr; Cp = qr;    N = 1024; bx -= 8; }
  else if (bx < 24) { Ap = nkv; K = 512;  Bp = wdkn; Cp = knope; N = 1024; bx -= 16; }
  else              { Ap = nkv; K = 512;  Bp = wdv;  Cp = vt;    N = 2048; bx -= 24; tv = true; }
  const int tid = threadIdx.x;
  const int lane = tid & 63;
  const int wid = tid >> 6;
  const int m0 = blockIdx.y * 128;
  const int n0 = bx * 128;
  const int wm = (wid >> 1) * 64;
  const int wn = (wid & 1) * 64;

  f32x4 acc[4][4];
#pragma unroll
  for (int m = 0; m < 4; ++m)
#pragma unroll
    for (int n = 0; n < 4; ++n) acc[m][n] = (f32x4){0.f, 0.f, 0.f, 0.f};

  const int ktiles = K >> 6;
  for (int kt = 0; kt < ktiles; ++kt) {
    const int k0 = kt << 6;
    __syncthreads();
#pragma unroll
    for (int i = 0; i < 4; ++i) {
      const int chunk = (i * 4 + wid) * 1024;
      const int o = chunk + lane * 16;
      const int row = o >> 7;
      const int cb = o & 127;
      const ushort_t* src = Ap + (long)(m0 + row) * K + (k0 + (cb >> 1));
      __builtin_amdgcn_global_load_lds((const __attribute__((address_space(1))) unsigned int*)src,
                                       (__attribute__((address_space(3))) unsigned int*)((char*)As + chunk),
                                       16, 0, 0);
    }
#pragma unroll
    for (int i = 0; i < 4; ++i) {
      const int chunk = (i * 4 + wid) * 1024;
      const int o = chunk + lane * 16;
      const int row = o >> 7;
      const int cb = o & 127;
      const ushort_t* src = Bp + (long)(n0 + row) * K + (k0 + (cb >> 1));
      __builtin_amdgcn_global_load_lds((const __attribute__((address_space(1))) unsigned int*)src,
                                       (__attribute__((address_space(3))) unsigned int*)((char*)Bs + chunk),
                                       16, 0, 0);
    }
    __syncthreads();
#pragma unroll
    for (int kk = 0; kk < 2; ++kk) {
      const int kb = kk * 32 + ((lane >> 4) << 3);
      short8 a[4], b[4];
#pragma unroll
      for (int m = 0; m < 4; ++m)
        a[m] = *(const short8*)(As + (wm + m * 16 + (lane & 15)) * 64 + kb);
#pragma unroll
      for (int n = 0; n < 4; ++n)
        b[n] = *(const short8*)(Bs + (wn + n * 16 + (lane & 15)) * 64 + kb);
#pragma unroll
      for (int m = 0; m < 4; ++m)
#pragma unroll
        for (int n = 0; n < 4; ++n)
          acc[m][n] = __builtin_amdgcn_mfma_f32_16x16x32_bf16(a[m], b[n], acc[m][n], 0, 0, 0);
    }
  }
  if (tv) {
    __syncthreads();
    const int lrb = wm + ((lane >> 4) << 2);
    const int ldb = wn + (lane & 15);
#pragma unroll
    for (int m = 0; m < 4; ++m)
#pragma unroll
      for (int n = 0; n < 4; ++n) {
        const int ld = ldb + n * 16;
#pragma unroll
        for (int j = 0; j < 4; ++j) {
          const int lr = lrb + m * 16 + j;
          *(ushort_t*)((char*)S + lr * 256 + ((2 * ld) ^ ((lr & 15) << 4))) = f2bf(acc[m][n][j]);
        }
      }
    __syncthreads();
    const int b = m0 >> 11;
    const int s0 = m0 & 2047;
    const int bh = b * 16 + bx;
    const int d = tid & 127;
    const int sh = (tid >> 7) * 64;
#pragma unroll
    for (int i = 0; i < 8; ++i) {
      const int sbase = sh + i * 8;
      short8 val;
#pragma unroll
      for (int j = 0; j < 8; ++j) {
        const int s = sbase + j;
        val[j] = (short)*(const ushort_t*)((const char*)S + s * 256 + ((2 * d) ^ ((s & 15) << 4)));
      }
      *(short8*)(Cp + ((long)bh * 128 + d) * 2048 + s0 + sbase) = val;
    }
    return;
  }
  const int rb = m0 + wm + ((lane >> 4) << 2);
  const int cbase = n0 + wn + (lane & 15);
#pragma unroll
  for (int m = 0; m < 4; ++m)
#pragma unroll
    for (int n = 0; n < 4; ++n) {
      const int c = cbase + n * 16;
#pragma unroll
      for (int j = 0; j < 4; ++j) {
        const long r = rb + m * 16 + j;
        Cp[r * N + c] = f2bf(acc[m][n][j]);
      }
    }
}

// ---------------- rmsnorm + rope_kraw merged ----------------
__device__ __forceinline__ void rms_body(const ushort_t* x, const float* w,
                                         ushort_t* out, int R, float* warr) {
  const int tid = threadIdx.x;
  float ss = 0.f;
  for (int i = tid; i < R; i += 256) { float v = bf2f(x[i]); ss += v * v; }
#pragma unroll
  for (int off = 32; off; off >>= 1) ss += __shfl_xor(ss, off);
  if ((tid & 63) == 0) warr[tid >> 6] = ss;
  __syncthreads();
  const float tot = warr[0] + warr[1] + warr[2] + warr[3];
  const float rs = rsqrtf(tot / (float)R + 1e-6f);
  for (int i = tid; i < R; i += 256) out[i] = f2bf(bf2f(x[i]) * rs * w[i]);
}

__device__ __forceinline__ void rope_body(const ushort_t* in, ushort_t* out,
                                          const float* fc, const float* fs,
                                          int heads, int bid) {
  const int idx = bid * 256 + threadIdx.x;
  const int i = idx & 31;
  const int rest = idx >> 5;
  const int hh = rest % heads;
  const int row = rest / heads;
  const int srow = row & 2047;
  const float c = fc[srow * 32 + i];
  const float s = fs[srow * 32 + i];
  const long base = (long)row * heads * 64 + hh * 64 + 2 * i;
  const float x0 = bf2f(in[base]);
  const float x1 = bf2f(in[base + 1]);
  out[base] = f2bf(x0 * c - x1 * s);
  out[base + 1] = f2bf(x0 * s + x1 * c);
}

__global__ __launch_bounds__(256)
void rms_rope(const ushort_t* __restrict__ ckv, const float* __restrict__ kvnw,
              ushort_t* __restrict__ nkv,
              const ushort_t* __restrict__ cq, const float* __restrict__ qnw,
              ushort_t* __restrict__ nq,
              const ushort_t* __restrict__ kraw, ushort_t* __restrict__ qrs,
              const float* __restrict__ fc, const float* __restrict__ fs) {
  __shared__ float warr[4];
  const int bid = blockIdx.x;
  if (bid < 4096) rms_body(ckv + (long)bid * 512, kvnw, nkv + (long)bid * 512, 512, warr);
  else if (bid < 8192) {
    const long row = bid - 4096;
    rms_body(cq + row * 1536, qnw, nq + row * 1536, 1536, warr);
  } else {
    rope_body(kraw, qrs, fc, fs, 1, bid - 8192);
  }
}

__global__ __launch_bounds__(256)
void rope_qr(const ushort_t* __restrict__ qr, ushort_t* __restrict__ krope,
             const float* __restrict__ fc, const float* __restrict__ fs) {
  rope_body(qr, krope, fc, fs, 16, blockIdx.x);
}

// ---------------- MFMA flash attention v10: v8 + full-width (row&15) swizzle ----------------
// Identical to round-15/17 v8 except the Ks/Vts swizzle mask widened 7->15
// (both sides: staging source pre-swizzle + read XOR). 256B rows have 16
// 16B slots; &7 only used 8 -> 8-way read conflict; &15 spreads to all 16
// -> 4-way. P buffer (128B rows) unchanged.
__global__ __launch_bounds__(512)
void attn_mfma(const ushort_t* __restrict__ qn, const ushort_t* __restrict__ qrs,
               const ushort_t* __restrict__ kn, const ushort_t* __restrict__ kr,
               const ushort_t* __restrict__ vt, ushort_t* __restrict__ out) {
  __shared__ __align__(16) ushort_t Ks[2][16384];   // [128 k][128 d], rows 256B, swizzled
  __shared__ __align__(16) ushort_t Vts[2][16384];  // [128 d][128 s], rows 256B, swizzled
  __shared__ __align__(16) ushort_t Ps[8192];       // per-wave [16 q][64 k] = 2048B x 8 waves
  const int tid = threadIdx.x, lane = tid & 63, wid = tid >> 6;
  const int g = lane >> 4, lq = lane & 15;
  const int bh = blockIdx.x, b = bh >> 4, h = bh & 15;
  const float scale = 0.08838834764831845f;  // 1/sqrt(128)
  char* Pbase = (char*)Ps + wid * 2048;

  auto stageK = [&](int bsel, int kt) {
    const int k0s = kt * 128;
#pragma unroll
    for (int i = 0; i < 4; ++i) {
      const int cc = wid * 4 + i;
      const int o = cc * 1024 + lane * 16;
      const int row = o >> 8;
      const int dK = ((o & 255) ^ ((row & 15) << 4)) >> 1;
      const long krow = (long)b * 2048 + k0s + row;
      const ushort_t* srcK = (dK < 64) ? (kn + krow * 1024 + h * 64 + dK)
                                       : (kr + krow * 1024 + h * 64 + (dK - 64));
      __builtin_amdgcn_global_load_lds((const __attribute__((address_space(1))) unsigned int*)srcK,
          (__attribute__((address_space(3))) unsigned int*)((char*)Ks[bsel] + cc * 1024), 16, 0, 0);
    }
  };
  auto stageV = [&](int bsel, int kt) {
    const int k0s = kt * 128;
#pragma unroll
    for (int i = 0; i < 4; ++i) {
      const int cc = wid * 4 + i;
      const int o = cc * 1024 + lane * 16;
      const int dr = o >> 8;
      const int se = ((o & 255) ^ ((dr & 15) << 4)) >> 1;
      const ushort_t* srcV = vt + ((long)bh * 128 + dr) * 2048 + k0s + se;
      __builtin_amdgcn_global_load_lds((const __attribute__((address_space(1))) unsigned int*)srcV,
          (__attribute__((address_space(3))) unsigned int*)((char*)Vts[bsel] + cc * 1024), 16, 0, 0);
    }
  };

  const int pair = blockIdx.y;
  for (int half = 0; half < 2; ++half) {
    const int tq = half ? (15 - pair) : pair;  // 128-row q-tile index
    const int q0 = tq * 128;
    const int qw0 = q0 + wid * 16;
    short8 aq[4];
    {
      const long grow = (long)b * 2048 + qw0 + lq;
#pragma unroll
      for (int ks = 0; ks < 4; ++ks) {
        const int d = ks * 32 + g * 8;
        const ushort_t* src = (d < 64) ? (qn + grow * 1024 + h * 64 + d)
                                       : (qrs + grow * 64 + (d - 64));
        aq[ks] = *(const short8*)src;
      }
    }
    f32x4 oacc[8];
#pragma unroll
    for (int n = 0; n < 8; ++n) oacc[n] = (f32x4){0.f, 0.f, 0.f, 0.f};
    float sm[4] = {-3e38f, -3e38f, -3e38f, -3e38f};
    float sl[4] = {0.f, 0.f, 0.f, 0.f};

    auto qk = [&](f32x4 (&sacc)[8], int u) {
#pragma unroll
      for (int n = 0; n < 8; ++n) sacc[n] = (f32x4){0.f, 0.f, 0.f, 0.f};
      const ushort_t* Kbuf = Ks[u & 1];
      __builtin_amdgcn_s_setprio(1);
#pragma unroll
      for (int ks = 0; ks < 4; ++ks) {
        const int x = ks * 64 + g * 16;
#pragma unroll
        for (int n = 0; n < 8; ++n) {
          const int kl = n * 16 + lq;
          short8 bk = *(const short8*)((const char*)Kbuf + kl * 256 + (x ^ ((kl & 15) << 4)));
          sacc[n] = __builtin_amdgcn_mfma_f32_16x16x32_bf16(aq[ks], bk, sacc[n], 0, 0, 0);
        }
      }
      __builtin_amdgcn_s_setprio(0);
    };
    auto process = [&](f32x4 (&sacc)[8], int u) {
      const int k0 = u * 128;
      if (k0 + 127 > qw0) {  // causal mask (wave-uniform condition)
#pragma unroll
        for (int n = 0; n < 8; ++n) {
          const int key = k0 + n * 16 + lq;
#pragma unroll
          for (int j = 0; j < 4; ++j) {
            const int qrow = qw0 + g * 4 + j;
            if (key > qrow) sacc[n][j] = -3e38f;
          }
        }
      }
      float tmax[4];
#pragma unroll
      for (int j = 0; j < 4; ++j) {
        float t0 = fmaxf(fmaxf(sacc[0][j], sacc[1][j]), fmaxf(sacc[2][j], sacc[3][j]));
        float t1 = fmaxf(fmaxf(sacc[4][j], sacc[5][j]), fmaxf(sacc[6][j], sacc[7][j]));
        tmax[j] = fmaxf(t0, t1);
      }
#pragma unroll
      for (int off = 1; off < 16; off <<= 1)
#pragma unroll
        for (int j = 0; j < 4; ++j) tmax[j] = fmaxf(tmax[j], __shfl_xor(tmax[j], off));
      bool need = false;
#pragma unroll
      for (int j = 0; j < 4; ++j) {
        tmax[j] *= scale;
        need = need || (tmax[j] > sm[j] + 8.f);
      }
      if (__any(need)) {
#pragma unroll
        for (int j = 0; j < 4; ++j) {
          const float mn = fmaxf(sm[j], tmax[j]);
          const float fr = __expf(sm[j] - mn);
          sm[j] = mn;
          sl[j] *= fr;
#pragma unroll
          for (int n = 0; n < 8; ++n) oacc[n][j] *= fr;
        }
      }
      f32x4 p[8];
#pragma unroll
      for (int n = 0; n < 8; ++n)
#pragma unroll
        for (int j = 0; j < 4; ++j)
          p[n][j] = __expf(__builtin_fmaf(sacc[n][j], scale, -sm[j]));
      float psum[4];
#pragma unroll
      for (int j = 0; j < 4; ++j) {
        psum[j] = ((p[0][j] + p[1][j]) + (p[2][j] + p[3][j])) +
                  ((p[4][j] + p[5][j]) + (p[6][j] + p[7][j]));
      }
#pragma unroll
      for (int off = 1; off < 16; off <<= 1)
#pragma unroll
        for (int j = 0; j < 4; ++j) psum[j] += __shfl_xor(psum[j], off);
#pragma unroll
      for (int j = 0; j < 4; ++j) sl[j] += psum[j];
      const ushort_t* Vbuf = Vts[u & 1];
#pragma unroll
      for (int hh = 0; hh < 2; ++hh) {
#pragma unroll
        for (int nn = 0; nn < 4; ++nn) {
          const int n = hh * 4 + nn;
          const int col2 = (nn * 16 + lq) * 2;
#pragma unroll
          for (int j = 0; j < 4; ++j) {
            const int row = g * 4 + j;
            *(ushort_t*)(Pbase + row * 128 + (col2 ^ ((row & 7) << 4))) = f2bf(p[n][j]);
          }
        }
        __builtin_amdgcn_s_setprio(1);
#pragma unroll
        for (int ks2 = 0; ks2 < 2; ++ks2) {
          const int x = ks2 * 64 + g * 16;
          short8 pa = *(const short8*)(Pbase + lq * 128 + (x ^ ((lq & 7) << 4)));
          const int xv = (hh * 2 + ks2) * 64 + g * 16;
#pragma unroll
          for (int nd = 0; nd < 8; ++nd) {
            const int dl = nd * 16 + lq;
            short8 vb = *(const short8*)((const char*)Vbuf + dl * 256 + (xv ^ ((dl & 15) << 4)));
            oacc[nd] = __builtin_amdgcn_mfma_f32_16x16x32_bf16(pa, vb, oacc[nd], 0, 0, 0);
          }
        }
        __builtin_amdgcn_s_setprio(0);
      }
    };

    const int kmax = tq + 1;  // 128-key tiles (may be odd)
    f32x4 saccA[8], saccB[8];
    // prologue
    stageK(0, 0); stageV(0, 0);
    if (kmax > 1) stageK(1, 1);
    asm volatile("s_waitcnt vmcnt(0)" ::: "memory");
    __builtin_amdgcn_s_barrier();
    __builtin_amdgcn_sched_barrier(0);
    qk(saccA, 0);
    int u = 0;
    for (; u + 1 < kmax; u += 2) {
      // ---- phase even: tile u ----
      if (u + 2 < kmax) stageK(0, u + 2);
      stageV(1, u + 1);
      qk(saccB, u + 1);      // MFMA reads Ks[1] — ∥ softmax below
      process(saccA, u);     // VALU + PV reads Vts[0]
      asm volatile("s_waitcnt vmcnt(0)" ::: "memory");
      __builtin_amdgcn_s_barrier();
      __builtin_amdgcn_sched_barrier(0);
      // ---- phase odd: tile u+1 ----
      if (u + 3 < kmax) stageK(1, u + 3);
      if (u + 2 < kmax) stageV(0, u + 2);
      if (u + 2 < kmax) qk(saccA, u + 2);
      process(saccB, u + 1);
      asm volatile("s_waitcnt vmcnt(0)" ::: "memory");
      __builtin_amdgcn_s_barrier();
      __builtin_amdgcn_sched_barrier(0);
    }
    if (u < kmax) {  // odd kmax: final tile (even parity -> saccA, Vts[0])
      process(saccA, u);
      __builtin_amdgcn_s_barrier();  // all reads done before next half restages
    }
    // ---- epilogue for this q-tile ----
    float inv[4];
#pragma unroll
    for (int j = 0; j < 4; ++j) inv[j] = 1.f / sl[j];
#pragma unroll
    for (int nd = 0; nd < 8; ++nd) {
      const int d = nd * 16 + lq;
#pragma unroll
      for (int j = 0; j < 4; ++j) {
        const long row = (long)b * 2048 + qw0 + g * 4 + j;
        out[row * 2048 + h * 128 + d] = f2bf(oacc[nd][j] * inv[j]);
      }
    }
  }
}

// ---------------- launch ----------------
// Workspace: EXACTLY 101,711,872 B (round-3-proven bound).
extern "C" void kernel_launch(void* const* d_in, const int* in_sizes, int n_in,
                              void* d_out, int out_size, void* d_ws, size_t ws_size,
                              hipStream_t stream) {
  const float* x      = (const float*)d_in[0];
  const float* fcos   = (const float*)d_in[1];
  const float* fsin   = (const float*)d_in[2];
  const float* w_cq   = (const float*)d_in[3];
  const float* w_dqn  = (const float*)d_in[4];
  const float* w_dqr  = (const float*)d_in[5];
  const float* w_ckv  = (const float*)d_in[6];
  const float* w_dkn  = (const float*)d_in[7];
  const float* w_dv   = (const float*)d_in[8];
  const float* w_kr   = (const float*)d_in[9];
  const float* w_proj = (const float*)d_in[10];
  const float* qnw    = (const float*)d_in[11];
  const float* kvnw   = (const float*)d_in[12];
  float* out = (float*)d_out;

  char* ws = (char*)d_ws;
  ushort_t* x_bf     = (ushort_t*)(ws + 0);
  ushort_t* wcq_bf   = (ushort_t*)(ws + 16777216);  // dead after step 2
  ushort_t* qrs_bf   = (ushort_t*)(ws + 16777216);  //   written step 3, read step 6
  ushort_t* wdqn_bf  = (ushort_t*)(ws + 23068672);
  ushort_t* wdqr_bf  = (ushort_t*)(ws + 26214400);
  ushort_t* wckv_bf  = (ushort_t*)(ws + 29360128);
  ushort_t* wdkn_bf  = (ushort_t*)(ws + 31457280);
  ushort_t* wdv_bf   = (ushort_t*)(ws + 32505856);
  ushort_t* wpr_bf   = (ushort_t*)(ws + 34603008);
  ushort_t* cq_bf    = (ushort_t*)(ws + 42991616);  // CQ region
  ushort_t* krope_bf = (ushort_t*)(ws + 42991616);  //   after cq dead (rope_qr, step 5)
  ushort_t* ckv_bf   = (ushort_t*)(ws + 55574528);  // CKVNQ region
  ushort_t* nq_bf    = (ushort_t*)(ws + 59768832);
  ushort_t* attn_bf  = (ushort_t*)(ws + 55574528);  //   after ckv/nq dead (step 6)
  ushort_t* nkv_bf   = (ushort_t*)(ws + 72351744);
  ushort_t* qnope_bf = (ushort_t*)(ws + 76546048);  // QNOPE region
  ushort_t* kraw_bf  = (ushort_t*)(ws + 76546048);  //   before qnope written (step 4)
  ushort_t* qr_bf    = (ushort_t*)(ws + 0);         // X region, after x_bf dead
  ushort_t* knope_bf = (ushort_t*)(ws + 8388608);
  ushort_t* wkr_bf   = (ushort_t*)(ws + 84934656);  // V region (dead after step 2)
  ushort_t* vt_bf    = (ushort_t*)(ws + 84934656);  //   vt written step 4

  // 1. all converts (8 elems/thread)
  cvt_all<<<10560, 256, 0, stream>>>(x, w_cq, w_dqn, w_dqr, w_ckv, w_dkn, w_dv, w_kr, w_proj,
                                     x_bf, wcq_bf, wdqn_bf, wdqr_bf, wckv_bf, wdkn_bf,
                                     wdv_bf, wkr_bf, wpr_bf);
  // 2. merged x-projections: [ckv 4 | cq 12 | kraw 1] blocks, K=2048
  gemm_bt3<<<dim3(17, 32), 256, 0, stream>>>(x_bf,
                                             wckv_bf, ckv_bf, 4, 512,
                                             wcq_bf, cq_bf, 12, 1536,
                                             wkr_bf, kraw_bf, 64, 2048);
  // 3. rmsnorms + rope kraw->qrs
  rms_rope<<<8704, 256, 0, stream>>>(ckv_bf, kvnw, nkv_bf, cq_bf, qnw, nq_bf,
                                     kraw_bf, qrs_bf, fcos, fsin);
  // 4. merged q+kv projections: [qnope 8 | qr 8 | knope 8 | vt 16]
  gemm_qkv<<<dim3(40, 32), 256, 0, stream>>>(nq_bf, nkv_bf,
                                             wdqn_bf, qnope_bf,
                                             wdqr_bf, qr_bf,
                                             wdkn_bf, knope_bf,
                                             wdv_bf, vt_bf);
  // 5. rope qr -> krope
  rope_qr<<<8192, 256, 0, stream>>>(qr_bf, krope_bf, fcos, fsin);
  // 6. MFMA flash attention v10 (v8 + full-width swizzle)
  attn_mfma<<<dim3(32, 8), 512, 0, stream>>>(qnope_bf, qrs_bf, knope_bf, krope_bf, vt_bf, attn_bf);
  // 7. final projection (fp32 out)
  gemm_bt<0><<<dim3(16, 32), 256, 0, stream>>>(attn_bf, wpr_bf, out, 4096, 2048, 2048);
}

// Round 19
// 325.526 us; speedup vs baseline: 1.0635x; 1.0200x over previous
//
#include <hip/hip_runtime.h>

typedef __attribute__((ext_vector_type(4))) float f32x4;
typedef __attribute__((ext_vector_type(8))) short short8;
typedef unsigned short ushort_t;

__device__ __forceinline__ float bf2f(ushort_t u) {
  unsigned int i = ((unsigned int)u) << 16;
  return __builtin_bit_cast(float, i);
}
__device__ __forceinline__ ushort_t f2bf(float f) {
  unsigned int x = __builtin_bit_cast(unsigned int, f);
  unsigned int r = (x + 0x7FFFu + ((x >> 16) & 1u)) >> 16;
  return (ushort_t)r;
}

// ---------------- fused fp32 -> bf16 convert: all 9 inputs, 8 elems/thread ----------------
__global__ __launch_bounds__(256)
void cvt_all(const float* __restrict__ x, const float* __restrict__ wcq,
             const float* __restrict__ wdqn, const float* __restrict__ wdqr,
             const float* __restrict__ wckv, const float* __restrict__ wdkn,
             const float* __restrict__ wdv, const float* __restrict__ wkr,
             const float* __restrict__ wpr,
             ushort_t* ox, ushort_t* owcq, ushort_t* owdqn, ushort_t* owdqr,
             ushort_t* owckv, ushort_t* owdkn, ushort_t* owdv, ushort_t* owkr,
             ushort_t* owpr) {
  int bid = blockIdx.x;
  const float* in; ushort_t* out;
  if (bid < 4096)      { in = x;    out = ox;    }
  else if (bid < 5632) { in = wcq;  out = owcq;  bid -= 4096; }
  else if (bid < 6400) { in = wdqn; out = owdqn; bid -= 5632; }
  else if (bid < 7168) { in = wdqr; out = owdqr; bid -= 6400; }
  else if (bid < 7680) { in = wckv; out = owckv; bid -= 7168; }
  else if (bid < 7936) { in = wdkn; out = owdkn; bid -= 7680; }
  else if (bid < 8448) { in = wdv;  out = owdv;  bid -= 7936; }
  else if (bid < 8512) { in = wkr;  out = owkr;  bid -= 8448; }
  else                 { in = wpr;  out = owpr;  bid -= 8512; }
  const long i = ((long)bid * 256 + threadIdx.x) * 8;
  float4 v0 = *(const float4*)(in + i);
  float4 v1 = *(const float4*)(in + i + 4);
  short8 o;
  o[0] = (short)f2bf(v0.x); o[1] = (short)f2bf(v0.y);
  o[2] = (short)f2bf(v0.z); o[3] = (short)f2bf(v0.w);
  o[4] = (short)f2bf(v1.x); o[5] = (short)f2bf(v1.y);
  o[6] = (short)f2bf(v1.z); o[7] = (short)f2bf(v1.w);
  *(short8*)(out + i) = o;
}

// ---------------- bf16 MFMA GEMM (single-output); grid = (M/128, N/128) ----------------
// XCD A-affinity: m-block on grid.x -> wgid%8 = mx%8 -> n-blocks sharing the
// A-panel co-locate on one XCD L2.
template <int OUT_BF16>
__global__ __launch_bounds__(256)
void gemm_bt(const ushort_t* __restrict__ A, const ushort_t* __restrict__ B,
             void* __restrict__ Cv, int M, int N, int K) {
  __shared__ __align__(16) ushort_t As[128 * 64];
  __shared__ __align__(16) ushort_t Bs[128 * 64];
  const int tid = threadIdx.x;
  const int lane = tid & 63;
  const int wid = tid >> 6;
  const int m0 = blockIdx.x * 128;
  const int n0 = blockIdx.y * 128;
  const int wm = (wid >> 1) * 64;
  const int wn = (wid & 1) * 64;

  f32x4 acc[4][4];
#pragma unroll
  for (int m = 0; m < 4; ++m)
#pragma unroll
    for (int n = 0; n < 4; ++n) acc[m][n] = (f32x4){0.f, 0.f, 0.f, 0.f};

  const int ktiles = K >> 6;
  for (int kt = 0; kt < ktiles; ++kt) {
    const int k0 = kt << 6;
    __syncthreads();
#pragma unroll
    for (int i = 0; i < 4; ++i) {
      const int chunk = (i * 4 + wid) * 1024;
      const int o = chunk + lane * 16;
      const int row = o >> 7;
      const int cb = o & 127;
      const ushort_t* src = A + (long)(m0 + row) * K + (k0 + (cb >> 1));
      __builtin_amdgcn_global_load_lds((const __attribute__((address_space(1))) unsigned int*)src,
                                       (__attribute__((address_space(3))) unsigned int*)((char*)As + chunk),
                                       16, 0, 0);
    }
#pragma unroll
    for (int i = 0; i < 4; ++i) {
      const int chunk = (i * 4 + wid) * 1024;
      const int o = chunk + lane * 16;
      const int row = o >> 7;
      const int cb = o & 127;
      int brow = n0 + row;
      if (brow > N - 1) brow = N - 1;
      const ushort_t* src = B + (long)brow * K + (k0 + (cb >> 1));
      __builtin_amdgcn_global_load_lds((const __attribute__((address_space(1))) unsigned int*)src,
                                       (__attribute__((address_space(3))) unsigned int*)((char*)Bs + chunk),
                                       16, 0, 0);
    }
    __syncthreads();
#pragma unroll
    for (int kk = 0; kk < 2; ++kk) {
      const int kb = kk * 32 + ((lane >> 4) << 3);
      short8 a[4], b[4];
#pragma unroll
      for (int m = 0; m < 4; ++m)
        a[m] = *(const short8*)(As + (wm + m * 16 + (lane & 15)) * 64 + kb);
#pragma unroll
      for (int n = 0; n < 4; ++n)
        b[n] = *(const short8*)(Bs + (wn + n * 16 + (lane & 15)) * 64 + kb);
#pragma unroll
      for (int m = 0; m < 4; ++m)
#pragma unroll
        for (int n = 0; n < 4; ++n)
          acc[m][n] = __builtin_amdgcn_mfma_f32_16x16x32_bf16(a[m], b[n], acc[m][n], 0, 0, 0);
    }
  }
  const int rb = m0 + wm + ((lane >> 4) << 2);
  const int cbase = n0 + wn + (lane & 15);
#pragma unroll
  for (int m = 0; m < 4; ++m)
#pragma unroll
    for (int n = 0; n < 4; ++n) {
      const int c = cbase + n * 16;
      if (c < N) {
#pragma unroll
        for (int j = 0; j < 4; ++j) {
          const long r = rb + m * 16 + j;
          if (OUT_BF16)
            ((ushort_t*)Cv)[r * N + c] = f2bf(acc[m][n][j]);
          else
            ((float*)Cv)[r * N + c] = acc[m][n][j];
        }
      }
    }
}

// ---------------- merged 3-output GEMM (x-projections); grid = (32, 17) ----------------
__global__ __launch_bounds__(256)
void gemm_bt3(const ushort_t* __restrict__ A,
              const ushort_t* __restrict__ B0, ushort_t* __restrict__ C0, int nb0, int N0,
              const ushort_t* __restrict__ B1, ushort_t* __restrict__ C1, int nb1, int N1,
              const ushort_t* __restrict__ B2, ushort_t* __restrict__ C2, int N2,
              int K) {
  __shared__ __align__(16) ushort_t As[128 * 64];
  __shared__ __align__(16) ushort_t Bs[128 * 64];
  int nb = blockIdx.y;  // n-route on grid.y (A-affinity: wgid%8 = blockIdx.x%8)
  const ushort_t* Bp; ushort_t* Cp; int N;
  if (nb < nb0)            { Bp = B0; Cp = C0; N = N0; }
  else if (nb < nb0 + nb1) { Bp = B1; Cp = C1; N = N1; nb -= nb0; }
  else                     { Bp = B2; Cp = C2; N = N2; nb -= nb0 + nb1; }
  const int tid = threadIdx.x;
  const int lane = tid & 63;
  const int wid = tid >> 6;
  const int m0 = blockIdx.x * 128;
  const int n0 = nb * 128;
  const int wm = (wid >> 1) * 64;
  const int wn = (wid & 1) * 64;

  f32x4 acc[4][4];
#pragma unroll
  for (int m = 0; m < 4; ++m)
#pragma unroll
    for (int n = 0; n < 4; ++n) acc[m][n] = (f32x4){0.f, 0.f, 0.f, 0.f};

  const int ktiles = K >> 6;
  for (int kt = 0; kt < ktiles; ++kt) {
    const int k0 = kt << 6;
    __syncthreads();
#pragma unroll
    for (int i = 0; i < 4; ++i) {
      const int chunk = (i * 4 + wid) * 1024;
      const int o = chunk + lane * 16;
      const int row = o >> 7;
      const int cb = o & 127;
      const ushort_t* src = A + (long)(m0 + row) * K + (k0 + (cb >> 1));
      __builtin_amdgcn_global_load_lds((const __attribute__((address_space(1))) unsigned int*)src,
                                       (__attribute__((address_space(3))) unsigned int*)((char*)As + chunk),
                                       16, 0, 0);
    }
#pragma unroll
    for (int i = 0; i < 4; ++i) {
      const int chunk = (i * 4 + wid) * 1024;
      const int o = chunk + lane * 16;
      const int row = o >> 7;
      const int cb = o & 127;
      int brow = n0 + row;
      if (brow > N - 1) brow = N - 1;
      const ushort_t* src = Bp + (long)brow * K + (k0 + (cb >> 1));
      __builtin_amdgcn_global_load_lds((const __attribute__((address_space(1))) unsigned int*)src,
                                       (__attribute__((address_space(3))) unsigned int*)((char*)Bs + chunk),
                                       16, 0, 0);
    }
    __syncthreads();
#pragma unroll
    for (int kk = 0; kk < 2; ++kk) {
      const int kb = kk * 32 + ((lane >> 4) << 3);
      short8 a[4], b[4];
#pragma unroll
      for (int m = 0; m < 4; ++m)
        a[m] = *(const short8*)(As + (wm + m * 16 + (lane & 15)) * 64 + kb);
#pragma unroll
      for (int n = 0; n < 4; ++n)
        b[n] = *(const short8*)(Bs + (wn + n * 16 + (lane & 15)) * 64 + kb);
#pragma unroll
      for (int m = 0; m < 4; ++m)
#pragma unroll
        for (int n = 0; n < 4; ++n)
          acc[m][n] = __builtin_amdgcn_mfma_f32_16x16x32_bf16(a[m], b[n], acc[m][n], 0, 0, 0);
    }
  }
  const int rb = m0 + wm + ((lane >> 4) << 2);
  const int cbase = n0 + wn + (lane & 15);
#pragma unroll
  for (int m = 0; m < 4; ++m)
#pragma unroll
    for (int n = 0; n < 4; ++n) {
      const int c = cbase + n * 16;
      if (c < N) {
#pragma unroll
        for (int j = 0; j < 4; ++j) {
          const long r = rb + m * 16 + j;
          Cp[r * N + c] = f2bf(acc[m][n][j]);
        }
      }
    }
}

// ---------------- merged 4-output GEMM (q & kv projections); grid = (32, 40) ----------------
__global__ __launch_bounds__(256)
void gemm_qkv(const ushort_t* __restrict__ nq, const ushort_t* __restrict__ nkv,
              const ushort_t* __restrict__ wdqn, ushort_t* __restrict__ qnope,
              const ushort_t* __restrict__ wdqr, ushort_t* __restrict__ qr,
              const ushort_t* __restrict__ wdkn, ushort_t* __restrict__ knope,
              const ushort_t* __restrict__ wdv, ushort_t* __restrict__ vt) {
  __shared__ __align__(16) ushort_t S[16384];  // As | Bs ; reused 32KB for transpose epilogue
  ushort_t* As = S;
  ushort_t* Bs = S + 8192;
  int nb = blockIdx.y;  // segment route on grid.y (A-affinity on grid.x)
  const ushort_t* Ap; const ushort_t* Bp; ushort_t* Cp; int N, K; bool tv = false;
  if (nb < 8)       { Ap = nq;  K = 1536; Bp = wdqn; Cp = qnope; N = 1024; }
  else if (nb < 16) { Ap = nq;  K = 1536; Bp = wdqr; Cp = qr;    N = 1024; nb -= 8; }
  else if (nb < 24) { Ap = nkv; K = 512;  Bp = wdkn; Cp = knope; N = 1024; nb -= 16; }
  else              { Ap = nkv; K = 512;  Bp = wdv;  Cp = vt;    N = 2048; nb -= 24; tv = true; }
  const int tid = threadIdx.x;
  const int lane = tid & 63;
  const int wid = tid >> 6;
  const int m0 = blockIdx.x * 128;
  const int n0 = nb * 128;
  const int wm = (wid >> 1) * 64;
  const int wn = (wid & 1) * 64;

  f32x4 acc[4][4];
#pragma unroll
  for (int m = 0; m < 4; ++m)
#pragma unroll
    for (int n = 0; n < 4; ++n) acc[m][n] = (f32x4){0.f, 0.f, 0.f, 0.f};

  const int ktiles = K >> 6;
  for (int kt = 0; kt < ktiles; ++kt) {
    const int k0 = kt << 6;
    __syncthreads();
#pragma unroll
    for (int i = 0; i < 4; ++i) {
      const int chunk = (i * 4 + wid) * 1024;
      const int o = chunk + lane * 16;
      const int row = o >> 7;
      const int cb = o & 127;
      const ushort_t* src = Ap + (long)(m0 + row) * K + (k0 + (cb >> 1));
      __builtin_amdgcn_global_load_lds((const __attribute__((address_space(1))) unsigned int*)src,
                                       (__attribute__((address_space(3))) unsigned int*)((char*)As + chunk),
                                       16, 0, 0);
    }
#pragma unroll
    for (int i = 0; i < 4; ++i) {
      const int chunk = (i * 4 + wid) * 1024;
      const int o = chunk + lane * 16;
      const int row = o >> 7;
      const int cb = o & 127;
      const ushort_t* src = Bp + (long)(n0 + row) * K + (k0 + (cb >> 1));
      __builtin_amdgcn_global_load_lds((const __attribute__((address_space(1))) unsigned int*)src,
                                       (__attribute__((address_space(3))) unsigned int*)((char*)Bs + chunk),
                                       16, 0, 0);
    }
    __syncthreads();
#pragma unroll
    for (int kk = 0; kk < 2; ++kk) {
      const int kb = kk * 32 + ((lane >> 4) << 3);
      short8 a[4], b[4];
#pragma unroll
      for (int m = 0; m < 4; ++m)
        a[m] = *(const short8*)(As + (wm + m * 16 + (lane & 15)) * 64 + kb);
#pragma unroll
      for (int n = 0; n < 4; ++n)
        b[n] = *(const short8*)(Bs + (wn + n * 16 + (lane & 15)) * 64 + kb);
#pragma unroll
      for (int m = 0; m < 4; ++m)
#pragma unroll
        for (int n = 0; n < 4; ++n)
          acc[m][n] = __builtin_amdgcn_mfma_f32_16x16x32_bf16(a[m], b[n], acc[m][n], 0, 0, 0);
    }
  }
  if (tv) {
    __syncthreads();
    const int lrb = wm + ((lane >> 4) << 2);
    const int ldb = wn + (lane & 15);
#pragma unroll
    for (int m = 0; m < 4; ++m)
#pragma unroll
      for (int n = 0; n < 4; ++n) {
        const int ld = ldb + n * 16;
#pragma unroll
        for (int j = 0; j < 4; ++j) {
          const int lr = lrb + m * 16 + j;
          *(ushort_t*)((char*)S + lr * 256 + ((2 * ld) ^ ((lr & 15) << 4))) = f2bf(acc[m][n][j]);
        }
      }
    __syncthreads();
    const int b = m0 >> 11;
    const int s0 = m0 & 2047;
    const int bh = b * 16 + nb;  // nb = segment-local head index
    const int d = tid & 127;
    const int sh = (tid >> 7) * 64;
#pragma unroll
    for (int i = 0; i < 8; ++i) {
      const int sbase = sh + i * 8;
      short8 val;
#pragma unroll
      for (int j = 0; j < 8; ++j) {
        const int s = sbase + j;
        val[j] = (short)*(const ushort_t*)((const char*)S + s * 256 + ((2 * d) ^ ((s & 15) << 4)));
      }
      *(short8*)(Cp + ((long)bh * 128 + d) * 2048 + s0 + sbase) = val;
    }
    return;
  }
  const int rb = m0 + wm + ((lane >> 4) << 2);
  const int cbase = n0 + wn + (lane & 15);
#pragma unroll
  for (int m = 0; m < 4; ++m)
#pragma unroll
    for (int n = 0; n < 4; ++n) {
      const int c = cbase + n * 16;
#pragma unroll
      for (int j = 0; j < 4; ++j) {
        const long r = rb + m * 16 + j;
        Cp[r * N + c] = f2bf(acc[m][n][j]);
      }
    }
}

// ---------------- rmsnorm + rope_kraw merged ----------------
__device__ __forceinline__ void rms_body(const ushort_t* x, const float* w,
                                         ushort_t* out, int R, float* warr) {
  const int tid = threadIdx.x;
  float ss = 0.f;
  for (int i = tid; i < R; i += 256) { float v = bf2f(x[i]); ss += v * v; }
#pragma unroll
  for (int off = 32; off; off >>= 1) ss += __shfl_xor(ss, off);
  if ((tid & 63) == 0) warr[tid >> 6] = ss;
  __syncthreads();
  const float tot = warr[0] + warr[1] + warr[2] + warr[3];
  const float rs = rsqrtf(tot / (float)R + 1e-6f);
  for (int i = tid; i < R; i += 256) out[i] = f2bf(bf2f(x[i]) * rs * w[i]);
}

__device__ __forceinline__ void rope_body(const ushort_t* in, ushort_t* out,
                                          const float* fc, const float* fs,
                                          int heads, int bid) {
  const int idx = bid * 256 + threadIdx.x;
  const int i = idx & 31;
  const int rest = idx >> 5;
  const int hh = rest % heads;
  const int row = rest / heads;
  const int srow = row & 2047;
  const float c = fc[srow * 32 + i];
  const float s = fs[srow * 32 + i];
  const long base = (long)row * heads * 64 + hh * 64 + 2 * i;
  const float x0 = bf2f(in[base]);
  const float x1 = bf2f(in[base + 1]);
  out[base] = f2bf(x0 * c - x1 * s);
  out[base + 1] = f2bf(x0 * s + x1 * c);
}

__global__ __launch_bounds__(256)
void rms_rope(const ushort_t* __restrict__ ckv, const float* __restrict__ kvnw,
              ushort_t* __restrict__ nkv,
              const ushort_t* __restrict__ cq, const float* __restrict__ qnw,
              ushort_t* __restrict__ nq,
              const ushort_t* __restrict__ kraw, ushort_t* __restrict__ qrs,
              const float* __restrict__ fc, const float* __restrict__ fs) {
  __shared__ float warr[4];
  const int bid = blockIdx.x;
  if (bid < 4096) rms_body(ckv + (long)bid * 512, kvnw, nkv + (long)bid * 512, 512, warr);
  else if (bid < 8192) {
    const long row = bid - 4096;
    rms_body(cq + row * 1536, qnw, nq + row * 1536, 1536, warr);
  } else {
    rope_body(kraw, qrs, fc, fs, 1, bid - 8192);
  }
}

__global__ __launch_bounds__(256)
void rope_qr(const ushort_t* __restrict__ qr, ushort_t* __restrict__ krope,
             const float* __restrict__ fc, const float* __restrict__ fs) {
  rope_body(qr, krope, fc, fs, 16, blockIdx.x);
}

// ---------------- MFMA flash attention v10 (round-18: v8 + full-width swizzle) ----------------
__global__ __launch_bounds__(512)
void attn_mfma(const ushort_t* __restrict__ qn, const ushort_t* __restrict__ qrs,
               const ushort_t* __restrict__ kn, const ushort_t* __restrict__ kr,
               const ushort_t* __restrict__ vt, ushort_t* __restrict__ out) {
  __shared__ __align__(16) ushort_t Ks[2][16384];   // [128 k][128 d], rows 256B, swizzled
  __shared__ __align__(16) ushort_t Vts[2][16384];  // [128 d][128 s], rows 256B, swizzled
  __shared__ __align__(16) ushort_t Ps[8192];       // per-wave [16 q][64 k] = 2048B x 8 waves
  const int tid = threadIdx.x, lane = tid & 63, wid = tid >> 6;
  const int g = lane >> 4, lq = lane & 15;
  const int bh = blockIdx.x, b = bh >> 4, h = bh & 15;
  const float scale = 0.08838834764831845f;  // 1/sqrt(128)
  char* Pbase = (char*)Ps + wid * 2048;

  auto stageK = [&](int bsel, int kt) {
    const int k0s = kt * 128;
#pragma unroll
    for (int i = 0; i < 4; ++i) {
      const int cc = wid * 4 + i;
      const int o = cc * 1024 + lane * 16;
      const int row = o >> 8;
      const int dK = ((o & 255) ^ ((row & 15) << 4)) >> 1;
      const long krow = (long)b * 2048 + k0s + row;
      const ushort_t* srcK = (dK < 64) ? (kn + krow * 1024 + h * 64 + dK)
                                       : (kr + krow * 1024 + h * 64 + (dK - 64));
      __builtin_amdgcn_global_load_lds((const __attribute__((address_space(1))) unsigned int*)srcK,
          (__attribute__((address_space(3))) unsigned int*)((char*)Ks[bsel] + cc * 1024), 16, 0, 0);
    }
  };
  auto stageV = [&](int bsel, int kt) {
    const int k0s = kt * 128;
#pragma unroll
    for (int i = 0; i < 4; ++i) {
      const int cc = wid * 4 + i;
      const int o = cc * 1024 + lane * 16;
      const int dr = o >> 8;
      const int se = ((o & 255) ^ ((dr & 15) << 4)) >> 1;
      const ushort_t* srcV = vt + ((long)bh * 128 + dr) * 2048 + k0s + se;
      __builtin_amdgcn_global_load_lds((const __attribute__((address_space(1))) unsigned int*)srcV,
          (__attribute__((address_space(3))) unsigned int*)((char*)Vts[bsel] + cc * 1024), 16, 0, 0);
    }
  };

  const int pair = blockIdx.y;
  for (int half = 0; half < 2; ++half) {
    const int tq = half ? (15 - pair) : pair;  // 128-row q-tile index
    const int q0 = tq * 128;
    const int qw0 = q0 + wid * 16;
    short8 aq[4];
    {
      const long grow = (long)b * 2048 + qw0 + lq;
#pragma unroll
      for (int ks = 0; ks < 4; ++ks) {
        const int d = ks * 32 + g * 8;
        const ushort_t* src = (d < 64) ? (qn + grow * 1024 + h * 64 + d)
                                       : (qrs + grow * 64 + (d - 64));
        aq[ks] = *(const short8*)src;
      }
    }
    f32x4 oacc[8];
#pragma unroll
    for (int n = 0; n < 8; ++n) oacc[n] = (f32x4){0.f, 0.f, 0.f, 0.f};
    float sm[4] = {-3e38f, -3e38f, -3e38f, -3e38f};
    float sl[4] = {0.f, 0.f, 0.f, 0.f};

    auto qk = [&](f32x4 (&sacc)[8], int u) {
#pragma unroll
      for (int n = 0; n < 8; ++n) sacc[n] = (f32x4){0.f, 0.f, 0.f, 0.f};
      const ushort_t* Kbuf = Ks[u & 1];
      __builtin_amdgcn_s_setprio(1);
#pragma unroll
      for (int ks = 0; ks < 4; ++ks) {
        const int x = ks * 64 + g * 16;
#pragma unroll
        for (int n = 0; n < 8; ++n) {
          const int kl = n * 16 + lq;
          short8 bk = *(const short8*)((const char*)Kbuf + kl * 256 + (x ^ ((kl & 15) << 4)));
          sacc[n] = __builtin_amdgcn_mfma_f32_16x16x32_bf16(aq[ks], bk, sacc[n], 0, 0, 0);
        }
      }
      __builtin_amdgcn_s_setprio(0);
    };
    auto process = [&](f32x4 (&sacc)[8], int u) {
      const int k0 = u * 128;
      if (k0 + 127 > qw0) {  // causal mask (wave-uniform condition)
#pragma unroll
        for (int n = 0; n < 8; ++n) {
          const int key = k0 + n * 16 + lq;
#pragma unroll
          for (int j = 0; j < 4; ++j) {
            const int qrow = qw0 + g * 4 + j;
            if (key > qrow) sacc[n][j] = -3e38f;
          }
        }
      }
      float tmax[4];
#pragma unroll
      for (int j = 0; j < 4; ++j) {
        float t0 = fmaxf(fmaxf(sacc[0][j], sacc[1][j]), fmaxf(sacc[2][j], sacc[3][j]));
        float t1 = fmaxf(fmaxf(sacc[4][j], sacc[5][j]), fmaxf(sacc[6][j], sacc[7][j]));
        tmax[j] = fmaxf(t0, t1);
      }
#pragma unroll
      for (int off = 1; off < 16; off <<= 1)
#pragma unroll
        for (int j = 0; j < 4; ++j) tmax[j] = fmaxf(tmax[j], __shfl_xor(tmax[j], off));
      bool need = false;
#pragma unroll
      for (int j = 0; j < 4; ++j) {
        tmax[j] *= scale;
        need = need || (tmax[j] > sm[j] + 8.f);
      }
      if (__any(need)) {
#pragma unroll
        for (int j = 0; j < 4; ++j) {
          const float mn = fmaxf(sm[j], tmax[j]);
          const float fr = __expf(sm[j] - mn);
          sm[j] = mn;
          sl[j] *= fr;
#pragma unroll
          for (int n = 0; n < 8; ++n) oacc[n][j] *= fr;
        }
      }
      f32x4 p[8];
#pragma unroll
      for (int n = 0; n < 8; ++n)
#pragma unroll
        for (int j = 0; j < 4; ++j)
          p[n][j] = __expf(__builtin_fmaf(sacc[n][j], scale, -sm[j]));
      float psum[4];
#pragma unroll
      for (int j = 0; j < 4; ++j) {
        psum[j] = ((p[0][j] + p[1][j]) + (p[2][j] + p[3][j])) +
                  ((p[4][j] + p[5][j]) + (p[6][j] + p[7][j]));
      }
#pragma unroll
      for (int off = 1; off < 16; off <<= 1)
#pragma unroll
        for (int j = 0; j < 4; ++j) psum[j] += __shfl_xor(psum[j], off);
#pragma unroll
      for (int j = 0; j < 4; ++j) sl[j] += psum[j];
      const ushort_t* Vbuf = Vts[u & 1];
#pragma unroll
      for (int hh = 0; hh < 2; ++hh) {
#pragma unroll
        for (int nn = 0; nn < 4; ++nn) {
          const int n = hh * 4 + nn;
          const int col2 = (nn * 16 + lq) * 2;
#pragma unroll
          for (int j = 0; j < 4; ++j) {
            const int row = g * 4 + j;
            *(ushort_t*)(Pbase + row * 128 + (col2 ^ ((row & 7) << 4))) = f2bf(p[n][j]);
          }
        }
        __builtin_amdgcn_s_setprio(1);
#pragma unroll
        for (int ks2 = 0; ks2 < 2; ++ks2) {
          const int x = ks2 * 64 + g * 16;
          short8 pa = *(const short8*)(Pbase + lq * 128 + (x ^ ((lq & 7) << 4)));
          const int xv = (hh * 2 + ks2) * 64 + g * 16;
#pragma unroll
          for (int nd = 0; nd < 8; ++nd) {
            const int dl = nd * 16 + lq;
            short8 vb = *(const short8*)((const char*)Vbuf + dl * 256 + (xv ^ ((dl & 15) << 4)));
            oacc[nd] = __builtin_amdgcn_mfma_f32_16x16x32_bf16(pa, vb, oacc[nd], 0, 0, 0);
          }
        }
        __builtin_amdgcn_s_setprio(0);
      }
    };

    const int kmax = tq + 1;  // 128-key tiles (may be odd)
    f32x4 saccA[8], saccB[8];
    // prologue
    stageK(0, 0); stageV(0, 0);
    if (kmax > 1) stageK(1, 1);
    asm volatile("s_waitcnt vmcnt(0)" ::: "memory");
    __builtin_amdgcn_s_barrier();
    __builtin_amdgcn_sched_barrier(0);
    qk(saccA, 0);
    int u = 0;
    for (; u + 1 < kmax; u += 2) {
      // ---- phase even: tile u ----
      if (u + 2 < kmax) stageK(0, u + 2);
      stageV(1, u + 1);
      qk(saccB, u + 1);      // MFMA reads Ks[1] — ∥ softmax below
      process(saccA, u);     // VALU + PV reads Vts[0]
      asm volatile("s_waitcnt vmcnt(0)" ::: "memory");
      __builtin_amdgcn_s_barrier();
      __builtin_amdgcn_sched_barrier(0);
      // ---- phase odd: tile u+1 ----
      if (u + 3 < kmax) stageK(1, u + 3);
      if (u + 2 < kmax) stageV(0, u + 2);
      if (u + 2 < kmax) qk(saccA, u + 2);
      process(saccB, u + 1);
      asm volatile("s_waitcnt vmcnt(0)" ::: "memory");
      __builtin_amdgcn_s_barrier();
      __builtin_amdgcn_sched_barrier(0);
    }
    if (u < kmax) {  // odd kmax: final tile (even parity -> saccA, Vts[0])
      process(saccA, u);
      __builtin_amdgcn_s_barrier();  // all reads done before next half restages
    }
    // ---- epilogue for this q-tile ----
    float inv[4];
#pragma unroll
    for (int j = 0; j < 4; ++j) inv[j] = 1.f / sl[j];
#pragma unroll
    for (int nd = 0; nd < 8; ++nd) {
      const int d = nd * 16 + lq;
#pragma unroll
      for (int j = 0; j < 4; ++j) {
        const long row = (long)b * 2048 + qw0 + g * 4 + j;
        out[row * 2048 + h * 128 + d] = f2bf(oacc[nd][j] * inv[j]);
      }
    }
  }
}

// ---------------- launch ----------------
// Workspace: EXACTLY 101,711,872 B (round-3-proven bound).
extern "C" void kernel_launch(void* const* d_in, const int* in_sizes, int n_in,
                              void* d_out, int out_size, void* d_ws, size_t ws_size,
                              hipStream_t stream) {
  const float* x      = (const float*)d_in[0];
  const float* fcos   = (const float*)d_in[1];
  const float* fsin   = (const float*)d_in[2];
  const float* w_cq   = (const float*)d_in[3];
  const float* w_dqn  = (const float*)d_in[4];
  const float* w_dqr  = (const float*)d_in[5];
  const float* w_ckv  = (const float*)d_in[6];
  const float* w_dkn  = (const float*)d_in[7];
  const float* w_dv   = (const float*)d_in[8];
  const float* w_kr   = (const float*)d_in[9];
  const float* w_proj = (const float*)d_in[10];
  const float* qnw    = (const float*)d_in[11];
  const float* kvnw   = (const float*)d_in[12];
  float* out = (float*)d_out;

  char* ws = (char*)d_ws;
  ushort_t* x_bf     = (ushort_t*)(ws + 0);
  ushort_t* wcq_bf   = (ushort_t*)(ws + 16777216);  // dead after step 2
  ushort_t* qrs_bf   = (ushort_t*)(ws + 16777216);  //   written step 3, read step 6
  ushort_t* wdqn_bf  = (ushort_t*)(ws + 23068672);
  ushort_t* wdqr_bf  = (ushort_t*)(ws + 26214400);
  ushort_t* wckv_bf  = (ushort_t*)(ws + 29360128);
  ushort_t* wdkn_bf  = (ushort_t*)(ws + 31457280);
  ushort_t* wdv_bf   = (ushort_t*)(ws + 32505856);
  ushort_t* wpr_bf   = (ushort_t*)(ws + 34603008);
  ushort_t* cq_bf    = (ushort_t*)(ws + 42991616);  // CQ region
  ushort_t* krope_bf = (ushort_t*)(ws + 42991616);  //   after cq dead (rope_qr, step 5)
  ushort_t* ckv_bf   = (ushort_t*)(ws + 55574528);  // CKVNQ region
  ushort_t* nq_bf    = (ushort_t*)(ws + 59768832);
  ushort_t* attn_bf  = (ushort_t*)(ws + 55574528);  //   after ckv/nq dead (step 6)
  ushort_t* nkv_bf   = (ushort_t*)(ws + 72351744);
  ushort_t* qnope_bf = (ushort_t*)(ws + 76546048);  // QNOPE region
  ushort_t* kraw_bf  = (ushort_t*)(ws + 76546048);  //   before qnope written (step 4)
  ushort_t* qr_bf    = (ushort_t*)(ws + 0);         // X region, after x_bf dead
  ushort_t* knope_bf = (ushort_t*)(ws + 8388608);
  ushort_t* wkr_bf   = (ushort_t*)(ws + 84934656);  // V region (dead after step 2)
  ushort_t* vt_bf    = (ushort_t*)(ws + 84934656);  //   vt written step 4

  // 1. all converts (8 elems/thread)
  cvt_all<<<10560, 256, 0, stream>>>(x, w_cq, w_dqn, w_dqr, w_ckv, w_dkn, w_dv, w_kr, w_proj,
                                     x_bf, wcq_bf, wdqn_bf, wdqr_bf, wckv_bf, wdkn_bf,
                                     wdv_bf, wkr_bf, wpr_bf);
  // 2. merged x-projections: grid (m=32, route=17), A-affinity
  gemm_bt3<<<dim3(32, 17), 256, 0, stream>>>(x_bf,
                                             wckv_bf, ckv_bf, 4, 512,
                                             wcq_bf, cq_bf, 12, 1536,
                                             wkr_bf, kraw_bf, 64, 2048);
  // 3. rmsnorms + rope kraw->qrs
  rms_rope<<<8704, 256, 0, stream>>>(ckv_bf, kvnw, nkv_bf, cq_bf, qnw, nq_bf,
                                     kraw_bf, qrs_bf, fcos, fsin);
  // 4. merged q+kv projections: grid (m=32, route=40), A-affinity
  gemm_qkv<<<dim3(32, 40), 256, 0, stream>>>(nq_bf, nkv_bf,
                                             wdqn_bf, qnope_bf,
                                             wdqr_bf, qr_bf,
                                             wdkn_bf, knope_bf,
                                             wdv_bf, vt_bf);
  // 5. rope qr -> krope
  rope_qr<<<8192, 256, 0, stream>>>(qr_bf, krope_bf, fcos, fsin);
  // 6. MFMA flash attention v10
  attn_mfma<<<dim3(32, 8), 512, 0, stream>>>(qnope_bf, qrs_bf, knope_bf, krope_bf, vt_bf, attn_bf);
  // 7. final projection: grid (m=32, n=16), A-affinity (fp32 out)
  gemm_bt<0><<<dim3(32, 16), 256, 0, stream>>>(attn_bf, wpr_bf, out, 4096, 2048, 2048);
}